// Round 12
// baseline (963.021 us; speedup 1.0000x reference)
//
#include <hip/hip_runtime.h>
#include <math.h>

// ---------------- constants ----------------
#define EE 128
#define DI 256
#define HH 8
#define PP 32
#define NN 64
#define DC 4
#define XBC 384
#define DIN 648
#define NL 4
#define LSEQ 256
#define BB 256
#define TTOK (BB * LSEQ)   // 65536 tokens
#define EPSF 1e-5f

typedef __attribute__((ext_vector_type(8))) short short8;
typedef __attribute__((ext_vector_type(4))) float f32x4;

__device__ inline short f2bf(float f) {
  unsigned u = __builtin_bit_cast(unsigned, f);
  u += 0x7fff + ((u >> 16) & 1);   // RNE
  return (short)(u >> 16);
}
__device__ inline float bf2f(unsigned short u) {
  unsigned x = ((unsigned)u) << 16;
  return __builtin_bit_cast(float, x);
}

// ---------------- one-shot weight conversion fp32 -> bf16 ----------------
__global__ __launch_bounds__(256) void cvt_w_kernel(
    const float* __restrict__ in_w, const float* __restrict__ ow,
    unsigned short* __restrict__ in_wb, unsigned short* __restrict__ owb) {
  int i = blockIdx.x * 256 + threadIdx.x;   // grid covers NL*DIN*EE = 331776
  in_wb[i] = (unsigned short)f2bf(in_w[i]);
  if (i < NL * EE * DI) owb[i] = (unsigned short)f2bf(ow[i]);
}

// ---------------- in-proj GEMM: bf16 A,B; bf16 out (LDS-coalesced) + fp32 dt side-channel ----------------
__global__ __launch_bounds__(256) void gemm_in_proj(
    const unsigned short* __restrict__ A, const unsigned short* __restrict__ B,
    unsigned short* __restrict__ Czx, float* __restrict__ dtraw,
    int M, int N, int K) {
  __shared__ __align__(16) unsigned short smem[128 * 136];
  short (*As)[40] = (short(*)[40])smem;
  short (*Bs)[40] = (short(*)[40])(smem + 128 * 40);
  const int tid = threadIdx.x;
  const int lane = tid & 63, wid = tid >> 6;
  const int wm = wid >> 1, wn = wid & 1;
  const int m0 = blockIdx.x * 128, n0 = blockIdx.y * 128;
  const int r = tid >> 1, hf = tid & 1;
  const int lr = lane & 15, lk = (lane >> 4) * 8;
  f32x4 acc[4][4] = {};
  for (int k0 = 0; k0 < K; k0 += 32) {
    {
      const unsigned short* ap = A + (size_t)(m0 + r) * K + k0 + hf * 16;
      *(short8*)&As[r][hf * 16] = *(const short8*)(ap);
      *(short8*)&As[r][hf * 16 + 8] = *(const short8*)(ap + 8);
    }
    {
      short8 s0 = {}, s1 = {};
      if (n0 + r < N) {
        const unsigned short* bp = B + (size_t)(n0 + r) * K + k0 + hf * 16;
        s0 = *(const short8*)(bp);
        s1 = *(const short8*)(bp + 8);
      }
      *(short8*)&Bs[r][hf * 16] = s0;
      *(short8*)&Bs[r][hf * 16 + 8] = s1;
    }
    __syncthreads();
    short8 af[4], bfr[4];
#pragma unroll
    for (int mi = 0; mi < 4; ++mi) af[mi] = *(const short8*)&As[wm * 64 + mi * 16 + lr][lk];
#pragma unroll
    for (int ni = 0; ni < 4; ++ni) bfr[ni] = *(const short8*)&Bs[wn * 64 + ni * 16 + lr][lk];
#pragma unroll
    for (int mi = 0; mi < 4; ++mi)
#pragma unroll
      for (int ni = 0; ni < 4; ++ni)
        acc[mi][ni] = __builtin_amdgcn_mfma_f32_16x16x32_bf16(af[mi], bfr[ni], acc[mi][ni], 0, 0, 0);
    __syncthreads();
  }
  // epilogue: bf16 tile -> LDS, then coalesced 16B stores
  {
    unsigned short (*Vt)[136] = (unsigned short(*)[136])smem;
#pragma unroll
    for (int mi = 0; mi < 4; ++mi) {
#pragma unroll
      for (int ni = 0; ni < 4; ++ni) {
        int row0 = wm * 64 + mi * 16 + (lane >> 4) * 4;
        int col = wn * 64 + ni * 16 + lr;
#pragma unroll
        for (int j = 0; j < 4; ++j)
          Vt[row0 + j][col] = (unsigned short)f2bf(acc[mi][ni][j]);
      }
    }
    // dt raw side-channel: only tile n0==640, cols 640..647 (wn==0, ni==0, lr<8)
    if (n0 == 640 && wn == 0 && lr < 8) {
#pragma unroll
      for (int mi = 0; mi < 4; ++mi) {
        int row0 = m0 + wm * 64 + mi * 16 + (lane >> 4) * 4;
#pragma unroll
        for (int j = 0; j < 4; ++j)
          dtraw[(size_t)(row0 + j) * 8 + lr] = acc[mi][0][j];
      }
    }
    __syncthreads();
    const int row = tid >> 4, cs = (tid & 15) * 8;
#pragma unroll
    for (int it = 0; it < 8; ++it) {
      int rr2 = it * 16 + row;
      if (n0 + cs < N)
        *(uint4*)(Czx + (size_t)(m0 + rr2) * DIN + n0 + cs) = *(const uint4*)&Vt[rr2][cs];
    }
  }
}

// ---------------- fused gate+RMS + out-proj + residual + next-LN (128-token tile) ----------------
// Pass1: gA = bf16(ysc*silu(z)*nw) into LDS (A operand), per-row rms -> rs_gate.
// K-loop: acc = gA @ owb^T (rms rsqrt commutes to epilogue). Epilogue: acc*rs_gate
// + residual -> tres fp32, Vt bf16 (aliased over gA), stats, next-LN -> tnb bf16.
__global__ __launch_bounds__(256) void gemm_out_gated_ln(
    const unsigned short* __restrict__ ysc, const unsigned short* __restrict__ zx,
    const float* __restrict__ nw, const unsigned short* __restrict__ B,
    float* __restrict__ tres, const float* __restrict__ lnw,
    const float* __restrict__ lnb, unsigned* __restrict__ tnb) {
  __shared__ __align__(16) unsigned short gA[128][264];   // 67.6 KB; Vt aliases after K-loop
  __shared__ short Bs[128][40];                            // 10.2 KB
  __shared__ float rs_gate[128], mu_s[128], rs_s[128];
  unsigned short (*Vt)[136] = (unsigned short(*)[136])&gA[0][0];
  const int tid = threadIdx.x;
  const int lane = tid & 63, wid = tid >> 6;
  const int wm = wid >> 1, wn = wid & 1;
  const int m0 = blockIdx.x * 128;
  const int lr = lane & 15, lk = (lane >> 4) * 8;
  const int r = tid >> 1, hf = tid & 1;
  // ---- pass 1: gate + rms -> gA ----
  {
    const unsigned short* yrow = ysc + (size_t)(m0 + r) * DI + hf * 128;
    const unsigned short* zrow = zx + (size_t)(m0 + r) * DIN + hf * 128;
    const float* nwp = nw + hf * 128;
    float ss = 0.f;
#pragma unroll
    for (int kk = 0; kk < 16; ++kk) {
      short8 yv = *(const short8*)(yrow + kk * 8);
      short8 zv = *(const short8*)(zrow + kk * 8);
      float4 nw0 = *(const float4*)(nwp + kk * 8);
      float4 nw1 = *(const float4*)(nwp + kk * 8 + 4);
      float nwv[8] = {nw0.x, nw0.y, nw0.z, nw0.w, nw1.x, nw1.y, nw1.z, nw1.w};
      short8 g8;
#pragma unroll
      for (int j = 0; j < 8; ++j) {
        float y = bf2f((unsigned short)yv[j]);
        float z = bf2f((unsigned short)zv[j]);
        float gr = y * (z / (1.f + expf(-z)));
        ss += gr * gr;
        g8[j] = f2bf(gr * nwv[j]);
      }
      *(short8*)&gA[r][hf * 128 + kk * 8] = g8;
    }
    ss += __shfl_xor(ss, 1);
    if (hf == 0) rs_gate[r] = rsqrtf(ss * (1.f / 256.f) + EPSF);
  }
  __syncthreads();
  // ---- K-loop: acc = gA @ B^T ----
  f32x4 acc[4][4] = {};
  for (int k0 = 0; k0 < 256; k0 += 32) {
    {
      const unsigned short* bp = B + (size_t)r * 256 + k0 + hf * 16;
      *(short8*)&Bs[r][hf * 16] = *(const short8*)(bp);
      *(short8*)&Bs[r][hf * 16 + 8] = *(const short8*)(bp + 8);
    }
    __syncthreads();
    short8 af[4], bfr[4];
#pragma unroll
    for (int mi = 0; mi < 4; ++mi) af[mi] = *(const short8*)&gA[wm * 64 + mi * 16 + lr][k0 + lk];
#pragma unroll
    for (int ni = 0; ni < 4; ++ni) bfr[ni] = *(const short8*)&Bs[wn * 64 + ni * 16 + lr][lk];
#pragma unroll
    for (int mi = 0; mi < 4; ++mi)
#pragma unroll
      for (int ni = 0; ni < 4; ++ni)
        acc[mi][ni] = __builtin_amdgcn_mfma_f32_16x16x32_bf16(af[mi], bfr[ni], acc[mi][ni], 0, 0, 0);
    __syncthreads();
  }
  // ---- epilogue: rr scale + residual + Vt (aliases gA; safe after final barrier) ----
#pragma unroll
  for (int mi = 0; mi < 4; ++mi) {
#pragma unroll
    for (int ni = 0; ni < 4; ++ni) {
      int row0 = wm * 64 + mi * 16 + (lane >> 4) * 4;
      int col = wn * 64 + ni * 16 + lr;
#pragma unroll
      for (int j = 0; j < 4; ++j) {
        int row = row0 + j;
        size_t idx = (size_t)(m0 + row) * 128 + col;
        float v = acc[mi][ni][j] * rs_gate[row] + tres[idx];
        tres[idx] = v;
        Vt[row][col] = (unsigned short)f2bf(v);
      }
    }
  }
  __syncthreads();
  // per-row stats (2 threads per row)
  {
    float s = 0.f, ss = 0.f;
#pragma unroll
    for (int kk = 0; kk < 8; ++kk) {
      short8 vv = *(const short8*)&Vt[r][hf * 64 + kk * 8];
#pragma unroll
      for (int j = 0; j < 8; ++j) {
        float f = bf2f((unsigned short)vv[j]);
        s += f; ss += f * f;
      }
    }
    s += __shfl_xor(s, 1);
    ss += __shfl_xor(ss, 1);
    if (hf == 0) {
      float mu = s * (1.f / 128.f);
      mu_s[r] = mu;
      rs_s[r] = rsqrtf(ss * (1.f / 128.f) - mu * mu + EPSF);
    }
  }
  __syncthreads();
  // next-LN write: packed bf16, coalesced
  float w0 = lnw[lane * 2], w1 = lnw[lane * 2 + 1];
  float b0 = lnb[lane * 2], b1 = lnb[lane * 2 + 1];
  for (int it = 0; it < 32; ++it) {
    int row = it * 4 + wid;
    float mu = mu_s[row], rr = rs_s[row];
    float v0 = bf2f(Vt[row][lane * 2]);
    float v1 = bf2f(Vt[row][lane * 2 + 1]);
    unsigned lo = (unsigned short)f2bf((v0 - mu) * rr * w0 + b0);
    unsigned hi = (unsigned short)f2bf((v1 - mu) * rr * w1 + b1);
    tnb[(size_t)(m0 + row) * 64 + lane] = lo | (hi << 16);
  }
}

// ---------------- patch-embed bf16 MFMA GEMM ----------------
__global__ __launch_bounds__(256) void gemm_bf16_patch(
    const float* __restrict__ X, const float* __restrict__ B,
    const float* __restrict__ bias, float* __restrict__ C) {
  __shared__ short As[128][40];
  __shared__ short Bs[128][40];
  const int tid = threadIdx.x;
  const int lane = tid & 63, wid = tid >> 6;
  const int wm = wid >> 1, wn = wid & 1;
  const int m0 = blockIdx.x * 128;
  const int r = tid >> 1, hf = tid & 1;
  const int lr = lane & 15, lk = (lane >> 4) * 8;
  const int m = m0 + r;
  const int bb = m >> 8, px = (m >> 4) & 15, py = m & 15;
  f32x4 acc[4][4] = {};
  for (int k0 = 0; k0 < 768; k0 += 32) {
    int k = k0 + hf * 16;
    int c = k >> 8, dx = (k >> 4) & 15;
    {
      const float* ap = X + (((size_t)(bb * 3 + c) * 256 + px * 16 + dx) * 256 + py * 16);
      float4 v0 = *(const float4*)(ap + 0);
      float4 v1 = *(const float4*)(ap + 4);
      float4 v2 = *(const float4*)(ap + 8);
      float4 v3 = *(const float4*)(ap + 12);
      short8 s0, s1;
      s0[0] = f2bf(v0.x); s0[1] = f2bf(v0.y); s0[2] = f2bf(v0.z); s0[3] = f2bf(v0.w);
      s0[4] = f2bf(v1.x); s0[5] = f2bf(v1.y); s0[6] = f2bf(v1.z); s0[7] = f2bf(v1.w);
      s1[0] = f2bf(v2.x); s1[1] = f2bf(v2.y); s1[2] = f2bf(v2.z); s1[3] = f2bf(v2.w);
      s1[4] = f2bf(v3.x); s1[5] = f2bf(v3.y); s1[6] = f2bf(v3.z); s1[7] = f2bf(v3.w);
      *(short8*)&As[r][hf * 16] = s0;
      *(short8*)&As[r][hf * 16 + 8] = s1;
    }
    {
      const float* bp = B + (size_t)r * 768 + k;
      float4 v0 = *(const float4*)(bp + 0);
      float4 v1 = *(const float4*)(bp + 4);
      float4 v2 = *(const float4*)(bp + 8);
      float4 v3 = *(const float4*)(bp + 12);
      short8 s0, s1;
      s0[0] = f2bf(v0.x); s0[1] = f2bf(v0.y); s0[2] = f2bf(v0.z); s0[3] = f2bf(v0.w);
      s0[4] = f2bf(v1.x); s0[5] = f2bf(v1.y); s0[6] = f2bf(v1.z); s0[7] = f2bf(v1.w);
      s1[0] = f2bf(v2.x); s1[1] = f2bf(v2.y); s1[2] = f2bf(v2.z); s1[3] = f2bf(v2.w);
      s1[4] = f2bf(v3.x); s1[5] = f2bf(v3.y); s1[6] = f2bf(v3.z); s1[7] = f2bf(v3.w);
      *(short8*)&Bs[r][hf * 16] = s0;
      *(short8*)&Bs[r][hf * 16 + 8] = s1;
    }
    __syncthreads();
    short8 af[4], bfr[4];
#pragma unroll
    for (int mi = 0; mi < 4; ++mi) af[mi] = *(const short8*)&As[wm * 64 + mi * 16 + lr][lk];
#pragma unroll
    for (int ni = 0; ni < 4; ++ni) bfr[ni] = *(const short8*)&Bs[wn * 64 + ni * 16 + lr][lk];
#pragma unroll
    for (int mi = 0; mi < 4; ++mi)
#pragma unroll
      for (int ni = 0; ni < 4; ++ni)
        acc[mi][ni] = __builtin_amdgcn_mfma_f32_16x16x32_bf16(af[mi], bfr[ni], acc[mi][ni], 0, 0, 0);
    __syncthreads();
  }
#pragma unroll
  for (int mi = 0; mi < 4; ++mi) {
#pragma unroll
    for (int ni = 0; ni < 4; ++ni) {
      int row0 = m0 + wm * 64 + mi * 16 + (lane >> 4) * 4;
      int col = wn * 64 + ni * 16 + (lane & 15);
#pragma unroll
      for (int j = 0; j < 4; ++j)
        C[(size_t)(row0 + j) * 128 + col] = acc[mi][ni][j] + bias[col];
    }
  }
}

// ---------------- LayerNorm over E=128, fp32 out (PE only) ----------------
__global__ __launch_bounds__(256) void ln_kernel(const float* in, float* out,
                                                 const float* __restrict__ w, const float* __restrict__ b) {
  int wid = threadIdx.x >> 6, lane = threadIdx.x & 63;
  size_t token = (size_t)blockIdx.x * 4 + wid;
  const float* p = in + token * 128;
  float2 v = *(const float2*)(p + lane * 2);
  float s = v.x + v.y;
#pragma unroll
  for (int off = 1; off < 64; off <<= 1) s += __shfl_xor(s, off);
  float mu = s * (1.f / 128.f);
  float dx = v.x - mu, dy = v.y - mu;
  float vs = dx * dx + dy * dy;
#pragma unroll
  for (int off = 1; off < 64; off <<= 1) vs += __shfl_xor(vs, off);
  float r = rsqrtf(vs * (1.f / 128.f) + EPSF);
  float2 o;
  o.x = dx * r * w[lane * 2 + 0] + b[lane * 2 + 0];
  o.y = dy * r * w[lane * 2 + 1] + b[lane * 2 + 1];
  *(float2*)(out + token * 128 + lane * 2) = o;
}

// ---------------- LayerNorm over E=128, bf16-packed out (pre-loop only) ----------------
__global__ __launch_bounds__(256) void ln_bf16_kernel(const float* in, unsigned* out,
                                                      const float* __restrict__ w, const float* __restrict__ b) {
  int wid = threadIdx.x >> 6, lane = threadIdx.x & 63;
  size_t token = (size_t)blockIdx.x * 4 + wid;
  const float* p = in + token * 128;
  float2 v = *(const float2*)(p + lane * 2);
  float s = v.x + v.y;
#pragma unroll
  for (int off = 1; off < 64; off <<= 1) s += __shfl_xor(s, off);
  float mu = s * (1.f / 128.f);
  float dx = v.x - mu, dy = v.y - mu;
  float vs = dx * dx + dy * dy;
#pragma unroll
  for (int off = 1; off < 64; off <<= 1) vs += __shfl_xor(vs, off);
  float r = rsqrtf(vs * (1.f / 128.f) + EPSF);
  unsigned lo = (unsigned short)f2bf(dx * r * w[lane * 2 + 0] + b[lane * 2 + 0]);
  unsigned hi = (unsigned short)f2bf(dy * r * w[lane * 2 + 1] + b[lane * 2 + 1]);
  out[token * 64 + lane] = lo | (hi << 16);
}

// ---------------- causal conv1d (DC=4) + SiLU, bf16 in/out ----------------
__global__ __launch_bounds__(256) void conv_silu_kernel(
    const unsigned short* __restrict__ zx, const float* __restrict__ cw,
    const float* __restrict__ cb, unsigned short* __restrict__ xbc) {
  int gid = blockIdx.x * 256 + threadIdx.x;  // T*96
  int token = gid / 96;
  int c4 = (gid - token * 96) * 4;
  int l = token & 255;
  const unsigned short* base = zx + (size_t)token * DIN + DI + c4;
  ushort4 z4 = make_ushort4(0, 0, 0, 0);
  ushort4 u0 = (l >= 3) ? *(const ushort4*)(base - 3 * DIN) : z4;
  ushort4 u1 = (l >= 2) ? *(const ushort4*)(base - 2 * DIN) : z4;
  ushort4 u2 = (l >= 1) ? *(const ushort4*)(base - 1 * DIN) : z4;
  ushort4 u3 = *(const ushort4*)(base);
  float4 w0 = *(const float4*)(cw + (c4 + 0) * 4);
  float4 w1 = *(const float4*)(cw + (c4 + 1) * 4);
  float4 w2 = *(const float4*)(cw + (c4 + 2) * 4);
  float4 w3 = *(const float4*)(cw + (c4 + 3) * 4);
  float4 cbv = *(const float4*)(cb + c4);
  float s0 = cbv.x + w0.x * bf2f(u0.x) + w0.y * bf2f(u1.x) + w0.z * bf2f(u2.x) + w0.w * bf2f(u3.x);
  float s1 = cbv.y + w1.x * bf2f(u0.y) + w1.y * bf2f(u1.y) + w1.z * bf2f(u2.y) + w1.w * bf2f(u3.y);
  float s2 = cbv.z + w2.x * bf2f(u0.z) + w2.y * bf2f(u1.z) + w2.z * bf2f(u2.z) + w2.w * bf2f(u3.z);
  float s3 = cbv.w + w3.x * bf2f(u0.w) + w3.y * bf2f(u1.w) + w3.z * bf2f(u2.w) + w3.w * bf2f(u3.w);
  s0 = s0 / (1.f + expf(-s0));
  s1 = s1 / (1.f + expf(-s1));
  s2 = s2 / (1.f + expf(-s2));
  s3 = s3 / (1.f + expf(-s3));
  unsigned a0 = (unsigned short)f2bf(s0), a1 = (unsigned short)f2bf(s1);
  unsigned a2 = (unsigned short)f2bf(s2), a3 = (unsigned short)f2bf(s3);
  uint2 o = make_uint2(a0 | (a1 << 16), a2 | (a3 << 16));
  *(uint2*)(xbc + (size_t)token * XBC + c4) = o;
}

// ---------------- dt = softplus(raw + bias); ldA = -exp(A_log)*dt ----------------
__global__ __launch_bounds__(256) void dt_kernel(
    const float* __restrict__ dtraw, const float* __restrict__ dtb,
    const float* __restrict__ A_log, float* __restrict__ dtv, float* __restrict__ ldAv) {
  int gid = blockIdx.x * 256 + threadIdx.x;  // T*8
  int h = gid & 7;
  float raw = dtraw[gid] + dtb[h];
  float dt = raw > 20.f ? raw : log1pf(expf(raw));
  dtv[gid] = dt;
  ldAv[gid] = -expf(A_log[h]) * dt;
}

// ---------------- chunked SSM scan via MFMA, packed-transpose staging ----------------
__global__ __launch_bounds__(256, 4) void scan_chunk_kernel(
    const unsigned short* __restrict__ xbc,  // [T][384] bf16
    const float* __restrict__ dtv,           // [T][8]
    const float* __restrict__ ldA,           // [T][8]
    const float* __restrict__ Dp,            // [8]
    unsigned short* __restrict__ ysc) {      // [T][256] bf16
  const int b = blockIdx.x & 255, h = blockIdx.x >> 8;
  const int tid = threadIdx.x;
  const int w = tid >> 6, lane = tid & 63;
  const int lr = lane & 15, lj = lane >> 4;
  __shared__ __align__(16) unsigned short Cb[64][72];   // C rows [t][n]; P after phase1
  __shared__ __align__(16) unsigned short Bb[64][72];   // B rows [s][n]
  __shared__ __align__(16) unsigned short BbT[64][72];  // [n][s]
  __shared__ __align__(16) unsigned short xT[32][72];   // [p][t]
  __shared__ __align__(16) unsigned short hbT[32][72];  // h [p][n]
  __shared__ float la[64], dtc[64], wt[64];
  for (int i = tid; i < 32 * 72 / 2; i += 256) ((unsigned*)hbT)[i] = 0;
  f32x4 acc_h[4] = {};   // waves 0,1 own h rows p = w*16 .. w*16+15
  const float dph = Dp[h];
  __syncthreads();

  for (int c = 0; c < 4; ++c) {
    const int tok0 = b * 256 + c * 64;
    if (w == 0) {
      float v = ldA[(size_t)(tok0 + lane) * 8 + h];
#pragma unroll
      for (int off = 1; off < 64; off <<= 1) {
        float u = __shfl_up(v, off);
        if (lane >= off) v += u;
      }
      la[lane] = v;
      dtc[lane] = dtv[(size_t)(tok0 + lane) * 8 + h];
    }
    for (int it = tid; it < 320; it += 256) {
      if (it < 64) {
        int pq = it & 3, tq = it >> 2;
        int t0 = tq * 4, p0 = pq * 8;
        const unsigned short* r0 = xbc + (size_t)(tok0 + t0) * XBC + h * 32 + p0;
        short8 a0 = *(const short8*)(r0);
        short8 a1 = *(const short8*)(r0 + XBC);
        short8 a2 = *(const short8*)(r0 + 2 * XBC);
        short8 a3 = *(const short8*)(r0 + 3 * XBC);
#pragma unroll
        for (int j = 0; j < 8; ++j) {
          ushort4 v;
          v.x = (unsigned short)a0[j]; v.y = (unsigned short)a1[j];
          v.z = (unsigned short)a2[j]; v.w = (unsigned short)a3[j];
          *(ushort4*)&xT[p0 + j][t0] = v;
        }
      } else if (it < 192) {
        int id = it - 64;
        int nq = id & 7, tq = id >> 3;
        int t0 = tq * 4, n0 = nq * 8;
        const unsigned short* r0 = xbc + (size_t)(tok0 + t0) * XBC + 256 + n0;
        short8 a0 = *(const short8*)(r0);
        short8 a1 = *(const short8*)(r0 + XBC);
        short8 a2 = *(const short8*)(r0 + 2 * XBC);
        short8 a3 = *(const short8*)(r0 + 3 * XBC);
        *(short8*)&Bb[t0 + 0][n0] = a0;
        *(short8*)&Bb[t0 + 1][n0] = a1;
        *(short8*)&Bb[t0 + 2][n0] = a2;
        *(short8*)&Bb[t0 + 3][n0] = a3;
#pragma unroll
        for (int j = 0; j < 8; ++j) {
          ushort4 v;
          v.x = (unsigned short)a0[j]; v.y = (unsigned short)a1[j];
          v.z = (unsigned short)a2[j]; v.w = (unsigned short)a3[j];
          *(ushort4*)&BbT[n0 + j][t0] = v;
        }
      } else {
        int id = it - 192;
        int nq = id & 7, tq = id >> 3;
        int t0 = tq * 4, n0 = nq * 8;
        const unsigned short* r0 = xbc + (size_t)(tok0 + t0) * XBC + 320 + n0;
        *(short8*)&Cb[t0 + 0][n0] = *(const short8*)(r0);
        *(short8*)&Cb[t0 + 1][n0] = *(const short8*)(r0 + XBC);
        *(short8*)&Cb[t0 + 2][n0] = *(const short8*)(r0 + 2 * XBC);
        *(short8*)&Cb[t0 + 3][n0] = *(const short8*)(r0 + 3 * XBC);
      }
    }
    __syncthreads();   // bar1
    if (w == 3) wt[lane] = __expf(la[63] - la[lane]) * dtc[lane];
    short8 afC0 = *(const short8*)&Cb[w * 16 + lr][lj * 8];
    short8 afC1 = *(const short8*)&Cb[w * 16 + lr][32 + lj * 8];
    f32x4 acc_s[4] = {};
#pragma unroll
    for (int ni = 0; ni < 4; ++ni) {
      short8 bf0 = *(const short8*)&Bb[ni * 16 + lr][lj * 8];
      short8 bf1 = *(const short8*)&Bb[ni * 16 + lr][32 + lj * 8];
      acc_s[ni] = __builtin_amdgcn_mfma_f32_16x16x32_bf16(afC0, bf0, acc_s[ni], 0, 0, 0);
      acc_s[ni] = __builtin_amdgcn_mfma_f32_16x16x32_bf16(afC1, bf1, acc_s[ni], 0, 0, 0);
    }
    f32x4 acc_y[2] = {};
#pragma unroll
    for (int ni = 0; ni < 2; ++ni) {
      short8 hf0 = *(const short8*)&hbT[ni * 16 + lr][lj * 8];
      short8 hf1 = *(const short8*)&hbT[ni * 16 + lr][32 + lj * 8];
      acc_y[ni] = __builtin_amdgcn_mfma_f32_16x16x32_bf16(afC0, hf0, acc_y[ni], 0, 0, 0);
      acc_y[ni] = __builtin_amdgcn_mfma_f32_16x16x32_bf16(afC1, hf1, acc_y[ni], 0, 0, 0);
    }
#pragma unroll
    for (int j = 0; j < 4; ++j) {
      float at = __expf(la[w * 16 + lj * 4 + j]);
      acc_y[0][j] *= at;
      acc_y[1][j] *= at;
    }
    __syncthreads();   // bar2
#pragma unroll
    for (int ni = 0; ni < 4; ++ni) {
      int s = ni * 16 + lr;
      float las = la[s], dts = dtc[s];
#pragma unroll
      for (int j = 0; j < 4; ++j) {
        int t = w * 16 + lj * 4 + j;
        float pv = 0.f;
        if (s <= t) pv = acc_s[ni][j] * __expf(la[t] - las) * dts;
        Cb[t][s] = (unsigned short)f2bf(pv);
      }
    }
    __syncthreads();   // bar3
    {
      short8 afP0 = *(const short8*)&Cb[w * 16 + lr][lj * 8];
      short8 afP1 = *(const short8*)&Cb[w * 16 + lr][32 + lj * 8];
#pragma unroll
      for (int ni = 0; ni < 2; ++ni) {
        short8 xf0 = *(const short8*)&xT[ni * 16 + lr][lj * 8];
        short8 xf1 = *(const short8*)&xT[ni * 16 + lr][32 + lj * 8];
        acc_y[ni] = __builtin_amdgcn_mfma_f32_16x16x32_bf16(afP0, xf0, acc_y[ni], 0, 0, 0);
        acc_y[ni] = __builtin_amdgcn_mfma_f32_16x16x32_bf16(afP1, xf1, acc_y[ni], 0, 0, 0);
      }
    }
    if (w < 2) {
      float aend = __expf(la[63]);
#pragma unroll
      for (int ni = 0; ni < 4; ++ni)
#pragma unroll
        for (int j = 0; j < 4; ++j) acc_h[ni][j] *= aend;
#pragma unroll
      for (int kk = 0; kk < 2; ++kk) {
        short8 xv = *(const short8*)&xT[w * 16 + lr][kk * 32 + lj * 8];
        short8 axf;
#pragma unroll
        for (int j = 0; j < 8; ++j)
          axf[j] = f2bf(bf2f((unsigned short)xv[j]) * wt[kk * 32 + lj * 8 + j]);
#pragma unroll
        for (int ni = 0; ni < 4; ++ni) {
          short8 bw = *(const short8*)&BbT[ni * 16 + lr][kk * 32 + lj * 8];
          acc_h[ni] = __builtin_amdgcn_mfma_f32_16x16x32_bf16(axf, bw, acc_h[ni], 0, 0, 0);
        }
      }
    }
#pragma unroll
    for (int ni = 0; ni < 2; ++ni) {
#pragma unroll
      for (int j = 0; j < 4; ++j) {
        int t = w * 16 + lj * 4 + j;
        int p = ni * 16 + lr;
        float yv = acc_y[ni][j] + dph * bf2f(xT[p][t]);
        ysc[(size_t)(tok0 + t) * DI + h * 32 + p] = (unsigned short)f2bf(yv);
      }
    }
    if (w < 2) {
#pragma unroll
      for (int ni = 0; ni < 4; ++ni)
#pragma unroll
        for (int j = 0; j < 4; ++j)
          hbT[w * 16 + lj * 4 + j][ni * 16 + lr] = (unsigned short)f2bf(acc_h[ni][j]);
    }
    __syncthreads();   // bar4
  }
}

// ---------------- column mean over L (bf16 in) ----------------
__global__ __launch_bounds__(128) void colmean_kernel(const unsigned short* __restrict__ tn,
                                                      float* __restrict__ tmean) {
  int b = blockIdx.x, e = threadIdx.x;
  const unsigned short* p = tn + (size_t)b * 256 * 128 + e;
  float acc = 0.f;
  for (int l = 0; l < 256; ++l) acc += bf2f(p[l * 128]);
  tmean[b * 128 + e] = acc * (1.f / 256.f);
}

// ---------------- head matmul + L2 normalize ----------------
__global__ __launch_bounds__(128) void head_kernel(
    const float* __restrict__ tmean, const float* __restrict__ hw,
    const float* __restrict__ hb, float* __restrict__ out) {
  __shared__ float tm[128];
  __shared__ float red[2];
  int b = blockIdx.x, o = threadIdx.x;
  tm[o] = tmean[b * 128 + o];
  __syncthreads();
  float acc = hb[o];
  for (int e = 0; e < 128; ++e) acc += tm[e] * hw[o * 128 + e];
  float ss = acc * acc;
#pragma unroll
  for (int off = 1; off < 64; off <<= 1) ss += __shfl_xor(ss, off);
  if ((o & 63) == 0) red[o >> 6] = ss;
  __syncthreads();
  float nrm = fmaxf(sqrtf(red[0] + red[1]), 1e-12f);
  out[b * 128 + o] = acc / nrm;
}

extern "C" void kernel_launch(void* const* d_in, const int* in_sizes, int n_in,
                              void* d_out, int out_size, void* d_ws, size_t ws_size,
                              hipStream_t stream) {
  const float* x      = (const float*)d_in[0];
  const float* conv_w = (const float*)d_in[1];
  const float* conv_b = (const float*)d_in[2];
  const float* pe_w   = (const float*)d_in[3];
  const float* pe_b   = (const float*)d_in[4];
  const float* ln_w   = (const float*)d_in[5];
  const float* ln_b   = (const float*)d_in[6];
  const float* in_w   = (const float*)d_in[7];
  const float* c1w    = (const float*)d_in[8];
  const float* c1b    = (const float*)d_in[9];
  const float* dtb    = (const float*)d_in[10];
  const float* A_log  = (const float*)d_in[11];
  const float* Dp     = (const float*)d_in[12];
  const float* nw     = (const float*)d_in[13];
  const float* ow     = (const float*)d_in[14];
  const float* fn_w   = (const float*)d_in[15];
  const float* fn_b   = (const float*)d_in[16];
  const float* hw     = (const float*)d_in[17];
  const float* hb     = (const float*)d_in[18];
  float* out = (float*)d_out;

  const size_t T = TTOK;
  char* w8 = (char*)d_ws;
  float*          t_buf = (float*)w8;            w8 += T * 128 * 4;   // residual fp32
  unsigned*       tnb   = (unsigned*)w8;         w8 += T * 128 * 2;   // ln out bf16
  unsigned short* zx    = (unsigned short*)w8;   w8 += T * (size_t)DIN * 2; // in-proj bf16
  unsigned short* xbc   = (unsigned short*)w8;   w8 += T * (size_t)XBC * 2; // conv out bf16
  float*          dtraw = (float*)w8;            w8 += T * 8 * 4;
  float*          dtv   = (float*)w8;            w8 += T * 8 * 4;
  float*          ldAv  = (float*)w8;            w8 += T * 8 * 4;
  unsigned short* ysc   = (unsigned short*)w8;   w8 += T * (size_t)DI * 2;  // scan out bf16
  float*          tmean = (float*)w8;            w8 += 256 * 128 * 4;
  unsigned short* in_wb = (unsigned short*)w8;   w8 += (size_t)NL * DIN * EE * 2;
  unsigned short* owb   = (unsigned short*)w8;   w8 += (size_t)NL * EE * DI * 2;
  if ((size_t)(w8 - (char*)d_ws) > ws_size) return;  // workspace too small

  // one-shot weight conversion (NL*DIN*EE = 331776 = 1296*256)
  cvt_w_kernel<<<1296, 256, 0, stream>>>(in_w, ow, in_wb, owb);

  // patch embed + bias, pe layernorm (fp32), first block LN (bf16)
  gemm_bf16_patch<<<dim3(512, 1), 256, 0, stream>>>(x, conv_w, conv_b, t_buf);
  ln_kernel<<<16384, 256, 0, stream>>>(t_buf, t_buf, pe_w, pe_b);
  ln_bf16_kernel<<<16384, 256, 0, stream>>>(t_buf, tnb, ln_w, ln_b);

  for (int i = 0; i < NL; ++i) {
    gemm_in_proj<<<dim3(512, 6), 256, 0, stream>>>(
        (const unsigned short*)tnb, in_wb + (size_t)i * DIN * EE, zx, dtraw, TTOK, DIN, EE);
    conv_silu_kernel<<<24576, 256, 0, stream>>>(zx, c1w + (size_t)i * XBC * DC, c1b + (size_t)i * XBC, xbc);
    dt_kernel<<<2048, 256, 0, stream>>>(dtraw, dtb + i * HH, A_log + i * HH, dtv, ldAv);
    scan_chunk_kernel<<<2048, 256, 0, stream>>>(xbc, dtv, ldAv, Dp + i * HH, ysc);
    const float* nlw = (i < NL - 1) ? (ln_w + (i + 1) * 128) : fn_w;
    const float* nlb = (i < NL - 1) ? (ln_b + (i + 1) * 128) : fn_b;
    gemm_out_gated_ln<<<512, 256, 0, stream>>>(
        ysc, zx, nw + i * DI, owb + (size_t)i * EE * DI, t_buf, nlw, nlb, tnb);
  }

  // tnb holds final-LN output (fused in last gemm_out_gated_ln)
  colmean_kernel<<<256, 128, 0, stream>>>((const unsigned short*)tnb, tmean);
  head_kernel<<<256, 128, 0, stream>>>(tmean, hw, hb, out);
}

// Round 13
// 931.376 us; speedup vs baseline: 1.0340x; 1.0340x over previous
//
#include <hip/hip_runtime.h>
#include <math.h>

// ---------------- constants ----------------
#define EE 128
#define DI 256
#define HH 8
#define PP 32
#define NN 64
#define DC 4
#define XBC 384
#define DIN 648
#define ZXS 640            // zx row stride (z 0..255 | xbc 256..639), dt split out
#define NL 4
#define LSEQ 256
#define BB 256
#define TTOK (BB * LSEQ)   // 65536 tokens
#define EPSF 1e-5f

typedef __attribute__((ext_vector_type(8))) short short8;
typedef __attribute__((ext_vector_type(4))) float f32x4;

__device__ inline short f2bf(float f) {
  unsigned u = __builtin_bit_cast(unsigned, f);
  u += 0x7fff + ((u >> 16) & 1);   // RNE
  return (short)(u >> 16);
}
__device__ inline float bf2f(unsigned short u) {
  unsigned x = ((unsigned)u) << 16;
  return __builtin_bit_cast(float, x);
}

// ---------------- one-shot weight conversion fp32 -> bf16 ----------------
__global__ __launch_bounds__(256) void cvt_w_kernel(
    const float* __restrict__ in_w, const float* __restrict__ ow,
    unsigned short* __restrict__ in_wb, unsigned short* __restrict__ owb) {
  int i = blockIdx.x * 256 + threadIdx.x;   // grid covers NL*DIN*EE = 331776
  in_wb[i] = (unsigned short)f2bf(in_w[i]);
  if (i < NL * EE * DI) owb[i] = (unsigned short)f2bf(ow[i]);
}

// ---------------- in-proj GEMM: bf16 A,B; bf16 out (LDS-coalesced), N=640 exact ----------------
__global__ __launch_bounds__(256) void gemm_in_proj(
    const unsigned short* __restrict__ A, const unsigned short* __restrict__ B,
    unsigned short* __restrict__ Czx, int K) {
  __shared__ __align__(16) unsigned short smem[128 * 136];
  short (*As)[40] = (short(*)[40])smem;
  short (*Bs)[40] = (short(*)[40])(smem + 128 * 40);
  const int tid = threadIdx.x;
  const int lane = tid & 63, wid = tid >> 6;
  const int wm = wid >> 1, wn = wid & 1;
  const int m0 = blockIdx.x * 128, n0 = blockIdx.y * 128;
  const int r = tid >> 1, hf = tid & 1;
  const int lr = lane & 15, lk = (lane >> 4) * 8;
  f32x4 acc[4][4] = {};
  for (int k0 = 0; k0 < K; k0 += 32) {
    {
      const unsigned short* ap = A + (size_t)(m0 + r) * K + k0 + hf * 16;
      *(short8*)&As[r][hf * 16] = *(const short8*)(ap);
      *(short8*)&As[r][hf * 16 + 8] = *(const short8*)(ap + 8);
    }
    {
      const unsigned short* bp = B + (size_t)(n0 + r) * K + k0 + hf * 16;
      *(short8*)&Bs[r][hf * 16] = *(const short8*)(bp);
      *(short8*)&Bs[r][hf * 16 + 8] = *(const short8*)(bp + 8);
    }
    __syncthreads();
    short8 af[4], bfr[4];
#pragma unroll
    for (int mi = 0; mi < 4; ++mi) af[mi] = *(const short8*)&As[wm * 64 + mi * 16 + lr][lk];
#pragma unroll
    for (int ni = 0; ni < 4; ++ni) bfr[ni] = *(const short8*)&Bs[wn * 64 + ni * 16 + lr][lk];
#pragma unroll
    for (int mi = 0; mi < 4; ++mi)
#pragma unroll
      for (int ni = 0; ni < 4; ++ni)
        acc[mi][ni] = __builtin_amdgcn_mfma_f32_16x16x32_bf16(af[mi], bfr[ni], acc[mi][ni], 0, 0, 0);
    __syncthreads();
  }
  // epilogue: bf16 tile -> LDS, then coalesced 16B stores
  {
    unsigned short (*Vt)[136] = (unsigned short(*)[136])smem;
#pragma unroll
    for (int mi = 0; mi < 4; ++mi) {
#pragma unroll
      for (int ni = 0; ni < 4; ++ni) {
        int row0 = wm * 64 + mi * 16 + (lane >> 4) * 4;
        int col = wn * 64 + ni * 16 + lr;
#pragma unroll
        for (int j = 0; j < 4; ++j)
          Vt[row0 + j][col] = (unsigned short)f2bf(acc[mi][ni][j]);
      }
    }
    __syncthreads();
    const int row = tid >> 4, cs = (tid & 15) * 8;
#pragma unroll
    for (int it = 0; it < 8; ++it) {
      int rr2 = it * 16 + row;
      *(uint4*)(Czx + (size_t)(m0 + rr2) * ZXS + n0 + cs) = *(const uint4*)&Vt[rr2][cs];
    }
  }
}

// ---------------- dt GEMV: raw = tnb . in_w[640+h]; dt=softplus(raw+dtb); ldA ----------------
// grid = T/32 blocks, 256 threads; thread = (token_local = tid>>3, h = tid&7).
__global__ __launch_bounds__(256) void dt_gemv_kernel(
    const unsigned* __restrict__ tnb, const unsigned short* __restrict__ wdt,
    const float* __restrict__ dtb, const float* __restrict__ A_log,
    float* __restrict__ dtv, float* __restrict__ ldAv) {
  __shared__ float ws[8][128];
  const int tid = threadIdx.x;
  for (int i = tid; i < 1024; i += 256) ws[i >> 7][i & 127] = bf2f(wdt[i]);
  __syncthreads();
  const int token = blockIdx.x * 32 + (tid >> 3);
  const int h = tid & 7;
  const unsigned* row = tnb + (size_t)token * 64;
  float acc = 0.f;
#pragma unroll
  for (int k = 0; k < 64; ++k) {
    unsigned u = row[k];
    acc += bf2f((unsigned short)(u & 0xffff)) * ws[h][k * 2];
    acc += bf2f((unsigned short)(u >> 16)) * ws[h][k * 2 + 1];
  }
  float raw = acc + dtb[h];
  float dt = raw > 20.f ? raw : log1pf(expf(raw));
  int gid = token * 8 + h;
  dtv[gid] = dt;
  ldAv[gid] = -expf(A_log[h]) * dt;
}

// ---------------- out-proj + residual + fused next-LayerNorm (128-token tile) ----------------
__global__ __launch_bounds__(256) void gemm_out_ln(
    const unsigned short* __restrict__ A, const unsigned short* __restrict__ B,
    float* __restrict__ tres, const float* __restrict__ lnw,
    const float* __restrict__ lnb, unsigned* __restrict__ tnb) {
  __shared__ short As[128][40];
  __shared__ short Bs[128][40];
  __shared__ unsigned short Vt[128][136];
  __shared__ float mu_s[128], rs_s[128];
  const int tid = threadIdx.x;
  const int lane = tid & 63, wid = tid >> 6;
  const int wm = wid >> 1, wn = wid & 1;
  const int m0 = blockIdx.x * 128;
  const int r = tid >> 1, hf = tid & 1;
  const int lr = lane & 15, lk = (lane >> 4) * 8;
  f32x4 acc[4][4] = {};
  for (int k0 = 0; k0 < 256; k0 += 32) {
    {
      const unsigned short* ap = A + (size_t)(m0 + r) * 256 + k0 + hf * 16;
      *(short8*)&As[r][hf * 16] = *(const short8*)(ap);
      *(short8*)&As[r][hf * 16 + 8] = *(const short8*)(ap + 8);
    }
    {
      const unsigned short* bp = B + (size_t)r * 256 + k0 + hf * 16;
      *(short8*)&Bs[r][hf * 16] = *(const short8*)(bp);
      *(short8*)&Bs[r][hf * 16 + 8] = *(const short8*)(bp + 8);
    }
    __syncthreads();
    short8 af[4], bfr[4];
#pragma unroll
    for (int mi = 0; mi < 4; ++mi) af[mi] = *(const short8*)&As[wm * 64 + mi * 16 + lr][lk];
#pragma unroll
    for (int ni = 0; ni < 4; ++ni) bfr[ni] = *(const short8*)&Bs[wn * 64 + ni * 16 + lr][lk];
#pragma unroll
    for (int mi = 0; mi < 4; ++mi)
#pragma unroll
      for (int ni = 0; ni < 4; ++ni)
        acc[mi][ni] = __builtin_amdgcn_mfma_f32_16x16x32_bf16(af[mi], bfr[ni], acc[mi][ni], 0, 0, 0);
    __syncthreads();
  }
  // epilogue: residual add, fp32 store, bf16 LDS tile
#pragma unroll
  for (int mi = 0; mi < 4; ++mi) {
#pragma unroll
    for (int ni = 0; ni < 4; ++ni) {
      int row0 = wm * 64 + mi * 16 + (lane >> 4) * 4;
      int col = wn * 64 + ni * 16 + lr;
#pragma unroll
      for (int j = 0; j < 4; ++j) {
        int row = row0 + j;
        size_t idx = (size_t)(m0 + row) * 128 + col;
        float v = acc[mi][ni][j] + tres[idx];
        tres[idx] = v;
        Vt[row][col] = (unsigned short)f2bf(v);
      }
    }
  }
  __syncthreads();
  // per-row stats (2 threads per row)
  {
    int row = tid >> 1;
    float s = 0.f, ss = 0.f;
#pragma unroll
    for (int kk = 0; kk < 8; ++kk) {
      short8 vv = *(const short8*)&Vt[row][hf * 64 + kk * 8];
#pragma unroll
      for (int j = 0; j < 8; ++j) {
        float f = bf2f((unsigned short)vv[j]);
        s += f; ss += f * f;
      }
    }
    s += __shfl_xor(s, 1);
    ss += __shfl_xor(ss, 1);
    if (hf == 0) {
      float mu = s * (1.f / 128.f);
      mu_s[row] = mu;
      rs_s[row] = rsqrtf(ss * (1.f / 128.f) - mu * mu + EPSF);
    }
  }
  __syncthreads();
  // LN write: packed bf16, coalesced
  float w0 = lnw[lane * 2], w1 = lnw[lane * 2 + 1];
  float b0 = lnb[lane * 2], b1 = lnb[lane * 2 + 1];
  for (int it = 0; it < 32; ++it) {
    int row = it * 4 + wid;
    float mu = mu_s[row], rr = rs_s[row];
    float v0 = bf2f(Vt[row][lane * 2]);
    float v1 = bf2f(Vt[row][lane * 2 + 1]);
    unsigned lo = (unsigned short)f2bf((v0 - mu) * rr * w0 + b0);
    unsigned hi = (unsigned short)f2bf((v1 - mu) * rr * w1 + b1);
    tnb[(size_t)(m0 + row) * 64 + lane] = lo | (hi << 16);
  }
}

// ---------------- patch-embed bf16 MFMA GEMM ----------------
__global__ __launch_bounds__(256) void gemm_bf16_patch(
    const float* __restrict__ X, const float* __restrict__ B,
    const float* __restrict__ bias, float* __restrict__ C) {
  __shared__ short As[128][40];
  __shared__ short Bs[128][40];
  const int tid = threadIdx.x;
  const int lane = tid & 63, wid = tid >> 6;
  const int wm = wid >> 1, wn = wid & 1;
  const int m0 = blockIdx.x * 128;
  const int r = tid >> 1, hf = tid & 1;
  const int lr = lane & 15, lk = (lane >> 4) * 8;
  const int m = m0 + r;
  const int bb = m >> 8, px = (m >> 4) & 15, py = m & 15;
  f32x4 acc[4][4] = {};
  for (int k0 = 0; k0 < 768; k0 += 32) {
    int k = k0 + hf * 16;
    int c = k >> 8, dx = (k >> 4) & 15;
    {
      const float* ap = X + (((size_t)(bb * 3 + c) * 256 + px * 16 + dx) * 256 + py * 16);
      float4 v0 = *(const float4*)(ap + 0);
      float4 v1 = *(const float4*)(ap + 4);
      float4 v2 = *(const float4*)(ap + 8);
      float4 v3 = *(const float4*)(ap + 12);
      short8 s0, s1;
      s0[0] = f2bf(v0.x); s0[1] = f2bf(v0.y); s0[2] = f2bf(v0.z); s0[3] = f2bf(v0.w);
      s0[4] = f2bf(v1.x); s0[5] = f2bf(v1.y); s0[6] = f2bf(v1.z); s0[7] = f2bf(v1.w);
      s1[0] = f2bf(v2.x); s1[1] = f2bf(v2.y); s1[2] = f2bf(v2.z); s1[3] = f2bf(v2.w);
      s1[4] = f2bf(v3.x); s1[5] = f2bf(v3.y); s1[6] = f2bf(v3.z); s1[7] = f2bf(v3.w);
      *(short8*)&As[r][hf * 16] = s0;
      *(short8*)&As[r][hf * 16 + 8] = s1;
    }
    {
      const float* bp = B + (size_t)r * 768 + k;
      float4 v0 = *(const float4*)(bp + 0);
      float4 v1 = *(const float4*)(bp + 4);
      float4 v2 = *(const float4*)(bp + 8);
      float4 v3 = *(const float4*)(bp + 12);
      short8 s0, s1;
      s0[0] = f2bf(v0.x); s0[1] = f2bf(v0.y); s0[2] = f2bf(v0.z); s0[3] = f2bf(v0.w);
      s0[4] = f2bf(v1.x); s0[5] = f2bf(v1.y); s0[6] = f2bf(v1.z); s0[7] = f2bf(v1.w);
      s1[0] = f2bf(v2.x); s1[1] = f2bf(v2.y); s1[2] = f2bf(v2.z); s1[3] = f2bf(v2.w);
      s1[4] = f2bf(v3.x); s1[5] = f2bf(v3.y); s1[6] = f2bf(v3.z); s1[7] = f2bf(v3.w);
      *(short8*)&Bs[r][hf * 16] = s0;
      *(short8*)&Bs[r][hf * 16 + 8] = s1;
    }
    __syncthreads();
    short8 af[4], bfr[4];
#pragma unroll
    for (int mi = 0; mi < 4; ++mi) af[mi] = *(const short8*)&As[wm * 64 + mi * 16 + lr][lk];
#pragma unroll
    for (int ni = 0; ni < 4; ++ni) bfr[ni] = *(const short8*)&Bs[wn * 64 + ni * 16 + lr][lk];
#pragma unroll
    for (int mi = 0; mi < 4; ++mi)
#pragma unroll
      for (int ni = 0; ni < 4; ++ni)
        acc[mi][ni] = __builtin_amdgcn_mfma_f32_16x16x32_bf16(af[mi], bfr[ni], acc[mi][ni], 0, 0, 0);
    __syncthreads();
  }
#pragma unroll
  for (int mi = 0; mi < 4; ++mi) {
#pragma unroll
    for (int ni = 0; ni < 4; ++ni) {
      int row0 = m0 + wm * 64 + mi * 16 + (lane >> 4) * 4;
      int col = wn * 64 + ni * 16 + (lane & 15);
#pragma unroll
      for (int j = 0; j < 4; ++j)
        C[(size_t)(row0 + j) * 128 + col] = acc[mi][ni][j] + bias[col];
    }
  }
}

// ---------------- LayerNorm over E=128, fp32 out (PE only) ----------------
__global__ __launch_bounds__(256) void ln_kernel(const float* in, float* out,
                                                 const float* __restrict__ w, const float* __restrict__ b) {
  int wid = threadIdx.x >> 6, lane = threadIdx.x & 63;
  size_t token = (size_t)blockIdx.x * 4 + wid;
  const float* p = in + token * 128;
  float2 v = *(const float2*)(p + lane * 2);
  float s = v.x + v.y;
#pragma unroll
  for (int off = 1; off < 64; off <<= 1) s += __shfl_xor(s, off);
  float mu = s * (1.f / 128.f);
  float dx = v.x - mu, dy = v.y - mu;
  float vs = dx * dx + dy * dy;
#pragma unroll
  for (int off = 1; off < 64; off <<= 1) vs += __shfl_xor(vs, off);
  float r = rsqrtf(vs * (1.f / 128.f) + EPSF);
  float2 o;
  o.x = dx * r * w[lane * 2 + 0] + b[lane * 2 + 0];
  o.y = dy * r * w[lane * 2 + 1] + b[lane * 2 + 1];
  *(float2*)(out + token * 128 + lane * 2) = o;
}

// ---------------- LayerNorm over E=128, bf16-packed out (pre-loop only) ----------------
__global__ __launch_bounds__(256) void ln_bf16_kernel(const float* in, unsigned* out,
                                                      const float* __restrict__ w, const float* __restrict__ b) {
  int wid = threadIdx.x >> 6, lane = threadIdx.x & 63;
  size_t token = (size_t)blockIdx.x * 4 + wid;
  const float* p = in + token * 128;
  float2 v = *(const float2*)(p + lane * 2);
  float s = v.x + v.y;
#pragma unroll
  for (int off = 1; off < 64; off <<= 1) s += __shfl_xor(s, off);
  float mu = s * (1.f / 128.f);
  float dx = v.x - mu, dy = v.y - mu;
  float vs = dx * dx + dy * dy;
#pragma unroll
  for (int off = 1; off < 64; off <<= 1) vs += __shfl_xor(vs, off);
  float r = rsqrtf(vs * (1.f / 128.f) + EPSF);
  unsigned lo = (unsigned short)f2bf(dx * r * w[lane * 2 + 0] + b[lane * 2 + 0]);
  unsigned hi = (unsigned short)f2bf(dy * r * w[lane * 2 + 1] + b[lane * 2 + 1]);
  out[token * 64 + lane] = lo | (hi << 16);
}

// ---------------- causal conv1d (DC=4) + SiLU, bf16 in/out ----------------
__global__ __launch_bounds__(256) void conv_silu_kernel(
    const unsigned short* __restrict__ zx, const float* __restrict__ cw,
    const float* __restrict__ cb, unsigned short* __restrict__ xbc) {
  int gid = blockIdx.x * 256 + threadIdx.x;  // T*96
  int token = gid / 96;
  int c4 = (gid - token * 96) * 4;
  int l = token & 255;
  const unsigned short* base = zx + (size_t)token * ZXS + DI + c4;
  ushort4 z4 = make_ushort4(0, 0, 0, 0);
  ushort4 u0 = (l >= 3) ? *(const ushort4*)(base - 3 * ZXS) : z4;
  ushort4 u1 = (l >= 2) ? *(const ushort4*)(base - 2 * ZXS) : z4;
  ushort4 u2 = (l >= 1) ? *(const ushort4*)(base - 1 * ZXS) : z4;
  ushort4 u3 = *(const ushort4*)(base);
  float4 w0 = *(const float4*)(cw + (c4 + 0) * 4);
  float4 w1 = *(const float4*)(cw + (c4 + 1) * 4);
  float4 w2 = *(const float4*)(cw + (c4 + 2) * 4);
  float4 w3 = *(const float4*)(cw + (c4 + 3) * 4);
  float4 cbv = *(const float4*)(cb + c4);
  float s0 = cbv.x + w0.x * bf2f(u0.x) + w0.y * bf2f(u1.x) + w0.z * bf2f(u2.x) + w0.w * bf2f(u3.x);
  float s1 = cbv.y + w1.x * bf2f(u0.y) + w1.y * bf2f(u1.y) + w1.z * bf2f(u2.y) + w1.w * bf2f(u3.y);
  float s2 = cbv.z + w2.x * bf2f(u0.z) + w2.y * bf2f(u1.z) + w2.z * bf2f(u2.z) + w2.w * bf2f(u3.z);
  float s3 = cbv.w + w3.x * bf2f(u0.w) + w3.y * bf2f(u1.w) + w3.z * bf2f(u2.w) + w3.w * bf2f(u3.w);
  s0 = s0 / (1.f + expf(-s0));
  s1 = s1 / (1.f + expf(-s1));
  s2 = s2 / (1.f + expf(-s2));
  s3 = s3 / (1.f + expf(-s3));
  unsigned a0 = (unsigned short)f2bf(s0), a1 = (unsigned short)f2bf(s1);
  unsigned a2 = (unsigned short)f2bf(s2), a3 = (unsigned short)f2bf(s3);
  uint2 o = make_uint2(a0 | (a1 << 16), a2 | (a3 << 16));
  *(uint2*)(xbc + (size_t)token * XBC + c4) = o;
}

// ---------------- chunked SSM scan via MFMA, packed-transpose staging ----------------
__global__ __launch_bounds__(256, 4) void scan_chunk_kernel(
    const unsigned short* __restrict__ xbc,  // [T][384] bf16
    const float* __restrict__ dtv,           // [T][8]
    const float* __restrict__ ldA,           // [T][8]
    const float* __restrict__ Dp,            // [8]
    unsigned short* __restrict__ ysc) {      // [T][256] bf16
  const int b = blockIdx.x & 255, h = blockIdx.x >> 8;
  const int tid = threadIdx.x;
  const int w = tid >> 6, lane = tid & 63;
  const int lr = lane & 15, lj = lane >> 4;
  __shared__ __align__(16) unsigned short Cb[64][72];   // C rows [t][n]; P after phase1
  __shared__ __align__(16) unsigned short Bb[64][72];   // B rows [s][n]
  __shared__ __align__(16) unsigned short BbT[64][72];  // [n][s]
  __shared__ __align__(16) unsigned short xT[32][72];   // [p][t]
  __shared__ __align__(16) unsigned short hbT[32][72];  // h [p][n]
  __shared__ float la[64], dtc[64], wt[64];
  for (int i = tid; i < 32 * 72 / 2; i += 256) ((unsigned*)hbT)[i] = 0;
  f32x4 acc_h[4] = {};   // waves 0,1 own h rows p = w*16 .. w*16+15
  const float dph = Dp[h];
  __syncthreads();

  for (int c = 0; c < 4; ++c) {
    const int tok0 = b * 256 + c * 64;
    if (w == 0) {
      float v = ldA[(size_t)(tok0 + lane) * 8 + h];
#pragma unroll
      for (int off = 1; off < 64; off <<= 1) {
        float u = __shfl_up(v, off);
        if (lane >= off) v += u;
      }
      la[lane] = v;
      dtc[lane] = dtv[(size_t)(tok0 + lane) * 8 + h];
    }
    for (int it = tid; it < 320; it += 256) {
      if (it < 64) {
        int pq = it & 3, tq = it >> 2;
        int t0 = tq * 4, p0 = pq * 8;
        const unsigned short* r0 = xbc + (size_t)(tok0 + t0) * XBC + h * 32 + p0;
        short8 a0 = *(const short8*)(r0);
        short8 a1 = *(const short8*)(r0 + XBC);
        short8 a2 = *(const short8*)(r0 + 2 * XBC);
        short8 a3 = *(const short8*)(r0 + 3 * XBC);
#pragma unroll
        for (int j = 0; j < 8; ++j) {
          ushort4 v;
          v.x = (unsigned short)a0[j]; v.y = (unsigned short)a1[j];
          v.z = (unsigned short)a2[j]; v.w = (unsigned short)a3[j];
          *(ushort4*)&xT[p0 + j][t0] = v;
        }
      } else if (it < 192) {
        int id = it - 64;
        int nq = id & 7, tq = id >> 3;
        int t0 = tq * 4, n0 = nq * 8;
        const unsigned short* r0 = xbc + (size_t)(tok0 + t0) * XBC + 256 + n0;
        short8 a0 = *(const short8*)(r0);
        short8 a1 = *(const short8*)(r0 + XBC);
        short8 a2 = *(const short8*)(r0 + 2 * XBC);
        short8 a3 = *(const short8*)(r0 + 3 * XBC);
        *(short8*)&Bb[t0 + 0][n0] = a0;
        *(short8*)&Bb[t0 + 1][n0] = a1;
        *(short8*)&Bb[t0 + 2][n0] = a2;
        *(short8*)&Bb[t0 + 3][n0] = a3;
#pragma unroll
        for (int j = 0; j < 8; ++j) {
          ushort4 v;
          v.x = (unsigned short)a0[j]; v.y = (unsigned short)a1[j];
          v.z = (unsigned short)a2[j]; v.w = (unsigned short)a3[j];
          *(ushort4*)&BbT[n0 + j][t0] = v;
        }
      } else {
        int id = it - 192;
        int nq = id & 7, tq = id >> 3;
        int t0 = tq * 4, n0 = nq * 8;
        const unsigned short* r0 = xbc + (size_t)(tok0 + t0) * XBC + 320 + n0;
        *(short8*)&Cb[t0 + 0][n0] = *(const short8*)(r0);
        *(short8*)&Cb[t0 + 1][n0] = *(const short8*)(r0 + XBC);
        *(short8*)&Cb[t0 + 2][n0] = *(const short8*)(r0 + 2 * XBC);
        *(short8*)&Cb[t0 + 3][n0] = *(const short8*)(r0 + 3 * XBC);
      }
    }
    __syncthreads();   // bar1
    if (w == 3) wt[lane] = __expf(la[63] - la[lane]) * dtc[lane];
    short8 afC0 = *(const short8*)&Cb[w * 16 + lr][lj * 8];
    short8 afC1 = *(const short8*)&Cb[w * 16 + lr][32 + lj * 8];
    f32x4 acc_s[4] = {};
#pragma unroll
    for (int ni = 0; ni < 4; ++ni) {
      short8 bf0 = *(const short8*)&Bb[ni * 16 + lr][lj * 8];
      short8 bf1 = *(const short8*)&Bb[ni * 16 + lr][32 + lj * 8];
      acc_s[ni] = __builtin_amdgcn_mfma_f32_16x16x32_bf16(afC0, bf0, acc_s[ni], 0, 0, 0);
      acc_s[ni] = __builtin_amdgcn_mfma_f32_16x16x32_bf16(afC1, bf1, acc_s[ni], 0, 0, 0);
    }
    f32x4 acc_y[2] = {};
#pragma unroll
    for (int ni = 0; ni < 2; ++ni) {
      short8 hf0 = *(const short8*)&hbT[ni * 16 + lr][lj * 8];
      short8 hf1 = *(const short8*)&hbT[ni * 16 + lr][32 + lj * 8];
      acc_y[ni] = __builtin_amdgcn_mfma_f32_16x16x32_bf16(afC0, hf0, acc_y[ni], 0, 0, 0);
      acc_y[ni] = __builtin_amdgcn_mfma_f32_16x16x32_bf16(afC1, hf1, acc_y[ni], 0, 0, 0);
    }
#pragma unroll
    for (int j = 0; j < 4; ++j) {
      float at = __expf(la[w * 16 + lj * 4 + j]);
      acc_y[0][j] *= at;
      acc_y[1][j] *= at;
    }
    __syncthreads();   // bar2
#pragma unroll
    for (int ni = 0; ni < 4; ++ni) {
      int s = ni * 16 + lr;
      float las = la[s], dts = dtc[s];
#pragma unroll
      for (int j = 0; j < 4; ++j) {
        int t = w * 16 + lj * 4 + j;
        float pv = 0.f;
        if (s <= t) pv = acc_s[ni][j] * __expf(la[t] - las) * dts;
        Cb[t][s] = (unsigned short)f2bf(pv);
      }
    }
    __syncthreads();   // bar3
    {
      short8 afP0 = *(const short8*)&Cb[w * 16 + lr][lj * 8];
      short8 afP1 = *(const short8*)&Cb[w * 16 + lr][32 + lj * 8];
#pragma unroll
      for (int ni = 0; ni < 2; ++ni) {
        short8 xf0 = *(const short8*)&xT[ni * 16 + lr][lj * 8];
        short8 xf1 = *(const short8*)&xT[ni * 16 + lr][32 + lj * 8];
        acc_y[ni] = __builtin_amdgcn_mfma_f32_16x16x32_bf16(afP0, xf0, acc_y[ni], 0, 0, 0);
        acc_y[ni] = __builtin_amdgcn_mfma_f32_16x16x32_bf16(afP1, xf1, acc_y[ni], 0, 0, 0);
      }
    }
    if (w < 2) {
      float aend = __expf(la[63]);
#pragma unroll
      for (int ni = 0; ni < 4; ++ni)
#pragma unroll
        for (int j = 0; j < 4; ++j) acc_h[ni][j] *= aend;
#pragma unroll
      for (int kk = 0; kk < 2; ++kk) {
        short8 xv = *(const short8*)&xT[w * 16 + lr][kk * 32 + lj * 8];
        short8 axf;
#pragma unroll
        for (int j = 0; j < 8; ++j)
          axf[j] = f2bf(bf2f((unsigned short)xv[j]) * wt[kk * 32 + lj * 8 + j]);
#pragma unroll
        for (int ni = 0; ni < 4; ++ni) {
          short8 bw = *(const short8*)&BbT[ni * 16 + lr][kk * 32 + lj * 8];
          acc_h[ni] = __builtin_amdgcn_mfma_f32_16x16x32_bf16(axf, bw, acc_h[ni], 0, 0, 0);
        }
      }
    }
#pragma unroll
    for (int ni = 0; ni < 2; ++ni) {
#pragma unroll
      for (int j = 0; j < 4; ++j) {
        int t = w * 16 + lj * 4 + j;
        int p = ni * 16 + lr;
        float yv = acc_y[ni][j] + dph * bf2f(xT[p][t]);
        ysc[(size_t)(tok0 + t) * DI + h * 32 + p] = (unsigned short)f2bf(yv);
      }
    }
    if (w < 2) {
#pragma unroll
      for (int ni = 0; ni < 4; ++ni)
#pragma unroll
        for (int j = 0; j < 4; ++j)
          hbT[w * 16 + lj * 4 + j][ni * 16 + lr] = (unsigned short)f2bf(acc_h[ni][j]);
    }
    __syncthreads();   // bar4
  }
}

// ---------------- y = rmsnorm(y * silu(z)) * nw -> bf16 (y bf16 in) ----------------
__global__ __launch_bounds__(256) void gate_rms_kernel(
    const unsigned short* __restrict__ ysc, const unsigned short* __restrict__ zx,
    const float* __restrict__ nw, unsigned short* __restrict__ yout) {
  int wid = threadIdx.x >> 6, lane = threadIdx.x & 63;
  size_t token = (size_t)blockIdx.x * 4 + wid;
  ushort4 yu = *(const ushort4*)(ysc + token * DI + lane * 4);
  ushort4 zu = *(const ushort4*)(zx + token * ZXS + lane * 4);
  float y0 = bf2f(yu.x), y1 = bf2f(yu.y), y2 = bf2f(yu.z), y3 = bf2f(yu.w);
  float z0 = bf2f(zu.x), z1 = bf2f(zu.y), z2 = bf2f(zu.z), z3 = bf2f(zu.w);
  float g0 = y0 * (z0 / (1.f + expf(-z0)));
  float g1 = y1 * (z1 / (1.f + expf(-z1)));
  float g2 = y2 * (z2 / (1.f + expf(-z2)));
  float g3 = y3 * (z3 / (1.f + expf(-z3)));
  float ss = g0 * g0 + g1 * g1 + g2 * g2 + g3 * g3;
#pragma unroll
  for (int off = 1; off < 64; off <<= 1) ss += __shfl_xor(ss, off);
  float r = rsqrtf(ss * (1.f / 256.f) + EPSF);
  unsigned w0 = (unsigned short)f2bf(g0 * r * nw[lane * 4 + 0]);
  unsigned w1 = (unsigned short)f2bf(g1 * r * nw[lane * 4 + 1]);
  unsigned w2 = (unsigned short)f2bf(g2 * r * nw[lane * 4 + 2]);
  unsigned w3 = (unsigned short)f2bf(g3 * r * nw[lane * 4 + 3]);
  uint2 packed = make_uint2(w0 | (w1 << 16), w2 | (w3 << 16));
  *(uint2*)(yout + token * DI + lane * 4) = packed;
}

// ---------------- column mean over L (bf16 in) ----------------
__global__ __launch_bounds__(128) void colmean_kernel(const unsigned short* __restrict__ tn,
                                                      float* __restrict__ tmean) {
  int b = blockIdx.x, e = threadIdx.x;
  const unsigned short* p = tn + (size_t)b * 256 * 128 + e;
  float acc = 0.f;
  for (int l = 0; l < 256; ++l) acc += bf2f(p[l * 128]);
  tmean[b * 128 + e] = acc * (1.f / 256.f);
}

// ---------------- head matmul + L2 normalize ----------------
__global__ __launch_bounds__(128) void head_kernel(
    const float* __restrict__ tmean, const float* __restrict__ hw,
    const float* __restrict__ hb, float* __restrict__ out) {
  __shared__ float tm[128];
  __shared__ float red[2];
  int b = blockIdx.x, o = threadIdx.x;
  tm[o] = tmean[b * 128 + o];
  __syncthreads();
  float acc = hb[o];
  for (int e = 0; e < 128; ++e) acc += tm[e] * hw[o * 128 + e];
  float ss = acc * acc;
#pragma unroll
  for (int off = 1; off < 64; off <<= 1) ss += __shfl_xor(ss, off);
  if ((o & 63) == 0) red[o >> 6] = ss;
  __syncthreads();
  float nrm = fmaxf(sqrtf(red[0] + red[1]), 1e-12f);
  out[b * 128 + o] = acc / nrm;
}

extern "C" void kernel_launch(void* const* d_in, const int* in_sizes, int n_in,
                              void* d_out, int out_size, void* d_ws, size_t ws_size,
                              hipStream_t stream) {
  const float* x      = (const float*)d_in[0];
  const float* conv_w = (const float*)d_in[1];
  const float* conv_b = (const float*)d_in[2];
  const float* pe_w   = (const float*)d_in[3];
  const float* pe_b   = (const float*)d_in[4];
  const float* ln_w   = (const float*)d_in[5];
  const float* ln_b   = (const float*)d_in[6];
  const float* in_w   = (const float*)d_in[7];
  const float* c1w    = (const float*)d_in[8];
  const float* c1b    = (const float*)d_in[9];
  const float* dtb    = (const float*)d_in[10];
  const float* A_log  = (const float*)d_in[11];
  const float* Dp     = (const float*)d_in[12];
  const float* nw     = (const float*)d_in[13];
  const float* ow     = (const float*)d_in[14];
  const float* fn_w   = (const float*)d_in[15];
  const float* fn_b   = (const float*)d_in[16];
  const float* hw     = (const float*)d_in[17];
  const float* hb     = (const float*)d_in[18];
  float* out = (float*)d_out;

  const size_t T = TTOK;
  char* w8 = (char*)d_ws;
  float*          t_buf = (float*)w8;            w8 += T * 128 * 4;   // residual fp32
  unsigned*       tnb   = (unsigned*)w8;         w8 += T * 128 * 2;   // ln out bf16
  unsigned short* zx    = (unsigned short*)w8;   w8 += T * (size_t)ZXS * 2; // in-proj bf16 (z|xbc)
  unsigned short* xbc   = (unsigned short*)w8;   w8 += T * (size_t)XBC * 2; // conv out bf16
  float*          dtv   = (float*)w8;            w8 += T * 8 * 4;
  float*          ldAv  = (float*)w8;            w8 += T * 8 * 4;
  unsigned short* ysc   = (unsigned short*)w8;   w8 += T * (size_t)DI * 2;  // scan out bf16
  unsigned short* ybb   = (unsigned short*)w8;   w8 += T * (size_t)DI * 2;  // gated bf16
  float*          tmean = (float*)w8;            w8 += 256 * 128 * 4;
  unsigned short* in_wb = (unsigned short*)w8;   w8 += (size_t)NL * DIN * EE * 2;
  unsigned short* owb   = (unsigned short*)w8;   w8 += (size_t)NL * EE * DI * 2;
  if ((size_t)(w8 - (char*)d_ws) > ws_size) return;  // workspace too small

  // one-shot weight conversion (NL*DIN*EE = 331776 = 1296*256)
  cvt_w_kernel<<<1296, 256, 0, stream>>>(in_w, ow, in_wb, owb);

  // patch embed + bias, pe layernorm (fp32), first block LN (bf16)
  gemm_bf16_patch<<<dim3(512, 1), 256, 0, stream>>>(x, conv_w, conv_b, t_buf);
  ln_kernel<<<16384, 256, 0, stream>>>(t_buf, t_buf, pe_w, pe_b);
  ln_bf16_kernel<<<16384, 256, 0, stream>>>(t_buf, tnb, ln_w, ln_b);

  for (int i = 0; i < NL; ++i) {
    const unsigned short* wlay = in_wb + (size_t)i * DIN * EE;
    gemm_in_proj<<<dim3(512, 5), 256, 0, stream>>>(
        (const unsigned short*)tnb, wlay, zx, EE);
    dt_gemv_kernel<<<2048, 256, 0, stream>>>(
        (const unsigned*)tnb, wlay + (size_t)(DI + XBC) * EE,
        dtb + i * HH, A_log + i * HH, dtv, ldAv);
    conv_silu_kernel<<<24576, 256, 0, stream>>>(zx, c1w + (size_t)i * XBC * DC, c1b + (size_t)i * XBC, xbc);
    scan_chunk_kernel<<<2048, 256, 0, stream>>>(xbc, dtv, ldAv, Dp + i * HH, ysc);
    gate_rms_kernel<<<16384, 256, 0, stream>>>(ysc, zx, nw + i * DI, ybb);
    const float* nlw = (i < NL - 1) ? (ln_w + (i + 1) * 128) : fn_w;
    const float* nlb = (i < NL - 1) ? (ln_b + (i + 1) * 128) : fn_b;
    gemm_out_ln<<<512, 256, 0, stream>>>(
        ybb, owb + (size_t)i * EE * DI, t_buf, nlw, nlb, tnb);
  }

  // tnb holds final-LN output (fused in last gemm_out_ln)
  colmean_kernel<<<256, 128, 0, stream>>>((const unsigned short*)tnb, tmean);
  head_kernel<<<256, 128, 0, stream>>>(tmean, hw, hb, out);
}

// Round 14
// 896.678 us; speedup vs baseline: 1.0740x; 1.0387x over previous
//
#include <hip/hip_runtime.h>
#include <math.h>

// ---------------- constants ----------------
#define EE 128
#define DI 256
#define HH 8
#define PP 32
#define NN 64
#define DC 4
#define XBC 384
#define DIN 648
#define NL 4
#define LSEQ 256
#define BB 256
#define TTOK (BB * LSEQ)   // 65536 tokens
#define EPSF 1e-5f

typedef __attribute__((ext_vector_type(8))) short short8;
typedef __attribute__((ext_vector_type(4))) float f32x4;

__device__ inline short f2bf(float f) {
  unsigned u = __builtin_bit_cast(unsigned, f);
  u += 0x7fff + ((u >> 16) & 1);   // RNE
  return (short)(u >> 16);
}
__device__ inline float bf2f(unsigned short u) {
  unsigned x = ((unsigned)u) << 16;
  return __builtin_bit_cast(float, x);
}

// ---------------- one-shot weight conversion fp32 -> bf16 ----------------
__global__ __launch_bounds__(256) void cvt_w_kernel(
    const float* __restrict__ in_w, const float* __restrict__ ow,
    unsigned short* __restrict__ in_wb, unsigned short* __restrict__ owb) {
  int i = blockIdx.x * 256 + threadIdx.x;   // grid covers NL*DIN*EE = 331776
  in_wb[i] = (unsigned short)f2bf(in_w[i]);
  if (i < NL * EE * DI) owb[i] = (unsigned short)f2bf(ow[i]);
}

// ---------------- in-proj GEMM: bf16 A,B; bf16 out (LDS-coalesced) + fp32 dt side-channel ----------------
__global__ __launch_bounds__(256) void gemm_in_proj(
    const unsigned short* __restrict__ A, const unsigned short* __restrict__ B,
    unsigned short* __restrict__ Czx, float* __restrict__ dtraw,
    int M, int N, int K) {
  __shared__ __align__(16) unsigned short smem[128 * 136];
  short (*As)[40] = (short(*)[40])smem;
  short (*Bs)[40] = (short(*)[40])(smem + 128 * 40);
  const int tid = threadIdx.x;
  const int lane = tid & 63, wid = tid >> 6;
  const int wm = wid >> 1, wn = wid & 1;
  const int m0 = blockIdx.x * 128, n0 = blockIdx.y * 128;
  const int r = tid >> 1, hf = tid & 1;
  const int lr = lane & 15, lk = (lane >> 4) * 8;
  f32x4 acc[4][4] = {};
  for (int k0 = 0; k0 < K; k0 += 32) {
    {
      const unsigned short* ap = A + (size_t)(m0 + r) * K + k0 + hf * 16;
      *(short8*)&As[r][hf * 16] = *(const short8*)(ap);
      *(short8*)&As[r][hf * 16 + 8] = *(const short8*)(ap + 8);
    }
    {
      short8 s0 = {}, s1 = {};
      if (n0 + r < N) {
        const unsigned short* bp = B + (size_t)(n0 + r) * K + k0 + hf * 16;
        s0 = *(const short8*)(bp);
        s1 = *(const short8*)(bp + 8);
      }
      *(short8*)&Bs[r][hf * 16] = s0;
      *(short8*)&Bs[r][hf * 16 + 8] = s1;
    }
    __syncthreads();
    short8 af[4], bfr[4];
#pragma unroll
    for (int mi = 0; mi < 4; ++mi) af[mi] = *(const short8*)&As[wm * 64 + mi * 16 + lr][lk];
#pragma unroll
    for (int ni = 0; ni < 4; ++ni) bfr[ni] = *(const short8*)&Bs[wn * 64 + ni * 16 + lr][lk];
#pragma unroll
    for (int mi = 0; mi < 4; ++mi)
#pragma unroll
      for (int ni = 0; ni < 4; ++ni)
        acc[mi][ni] = __builtin_amdgcn_mfma_f32_16x16x32_bf16(af[mi], bfr[ni], acc[mi][ni], 0, 0, 0);
    __syncthreads();
  }
  // epilogue: bf16 tile -> LDS, then coalesced 16B stores
  {
    unsigned short (*Vt)[136] = (unsigned short(*)[136])smem;
#pragma unroll
    for (int mi = 0; mi < 4; ++mi) {
#pragma unroll
      for (int ni = 0; ni < 4; ++ni) {
        int row0 = wm * 64 + mi * 16 + (lane >> 4) * 4;
        int col = wn * 64 + ni * 16 + lr;
#pragma unroll
        for (int j = 0; j < 4; ++j)
          Vt[row0 + j][col] = (unsigned short)f2bf(acc[mi][ni][j]);
      }
    }
    // dt raw side-channel: only tile n0==640, cols 640..647 (wn==0, ni==0, lr<8)
    if (n0 == 640 && wn == 0 && lr < 8) {
#pragma unroll
      for (int mi = 0; mi < 4; ++mi) {
        int row0 = m0 + wm * 64 + mi * 16 + (lane >> 4) * 4;
#pragma unroll
        for (int j = 0; j < 4; ++j)
          dtraw[(size_t)(row0 + j) * 8 + lr] = acc[mi][0][j];
      }
    }
    __syncthreads();
    const int row = tid >> 4, cs = (tid & 15) * 8;
#pragma unroll
    for (int it = 0; it < 8; ++it) {
      int rr2 = it * 16 + row;
      if (n0 + cs < N)
        *(uint4*)(Czx + (size_t)(m0 + rr2) * DIN + n0 + cs) = *(const uint4*)&Vt[rr2][cs];
    }
  }
}

// ---------------- out-proj + residual + fused next-LayerNorm (128-token tile) ----------------
__global__ __launch_bounds__(256) void gemm_out_ln(
    const unsigned short* __restrict__ A, const unsigned short* __restrict__ B,
    float* __restrict__ tres, const float* __restrict__ lnw,
    const float* __restrict__ lnb, unsigned* __restrict__ tnb) {
  __shared__ short As[128][40];
  __shared__ short Bs[128][40];
  __shared__ unsigned short Vt[128][136];
  __shared__ float mu_s[128], rs_s[128];
  const int tid = threadIdx.x;
  const int lane = tid & 63, wid = tid >> 6;
  const int wm = wid >> 1, wn = wid & 1;
  const int m0 = blockIdx.x * 128;
  const int r = tid >> 1, hf = tid & 1;
  const int lr = lane & 15, lk = (lane >> 4) * 8;
  f32x4 acc[4][4] = {};
  for (int k0 = 0; k0 < 256; k0 += 32) {
    {
      const unsigned short* ap = A + (size_t)(m0 + r) * 256 + k0 + hf * 16;
      *(short8*)&As[r][hf * 16] = *(const short8*)(ap);
      *(short8*)&As[r][hf * 16 + 8] = *(const short8*)(ap + 8);
    }
    {
      const unsigned short* bp = B + (size_t)r * 256 + k0 + hf * 16;
      *(short8*)&Bs[r][hf * 16] = *(const short8*)(bp);
      *(short8*)&Bs[r][hf * 16 + 8] = *(const short8*)(bp + 8);
    }
    __syncthreads();
    short8 af[4], bfr[4];
#pragma unroll
    for (int mi = 0; mi < 4; ++mi) af[mi] = *(const short8*)&As[wm * 64 + mi * 16 + lr][lk];
#pragma unroll
    for (int ni = 0; ni < 4; ++ni) bfr[ni] = *(const short8*)&Bs[wn * 64 + ni * 16 + lr][lk];
#pragma unroll
    for (int mi = 0; mi < 4; ++mi)
#pragma unroll
      for (int ni = 0; ni < 4; ++ni)
        acc[mi][ni] = __builtin_amdgcn_mfma_f32_16x16x32_bf16(af[mi], bfr[ni], acc[mi][ni], 0, 0, 0);
    __syncthreads();
  }
  // epilogue: residual add, fp32 store, bf16 LDS tile
#pragma unroll
  for (int mi = 0; mi < 4; ++mi) {
#pragma unroll
    for (int ni = 0; ni < 4; ++ni) {
      int row0 = wm * 64 + mi * 16 + (lane >> 4) * 4;
      int col = wn * 64 + ni * 16 + lr;
#pragma unroll
      for (int j = 0; j < 4; ++j) {
        int row = row0 + j;
        size_t idx = (size_t)(m0 + row) * 128 + col;
        float v = acc[mi][ni][j] + tres[idx];
        tres[idx] = v;
        Vt[row][col] = (unsigned short)f2bf(v);
      }
    }
  }
  __syncthreads();
  // per-row stats (2 threads per row)
  {
    int row = tid >> 1;
    float s = 0.f, ss = 0.f;
#pragma unroll
    for (int kk = 0; kk < 8; ++kk) {
      short8 vv = *(const short8*)&Vt[row][hf * 64 + kk * 8];
#pragma unroll
      for (int j = 0; j < 8; ++j) {
        float f = bf2f((unsigned short)vv[j]);
        s += f; ss += f * f;
      }
    }
    s += __shfl_xor(s, 1);
    ss += __shfl_xor(ss, 1);
    if (hf == 0) {
      float mu = s * (1.f / 128.f);
      mu_s[row] = mu;
      rs_s[row] = rsqrtf(ss * (1.f / 128.f) - mu * mu + EPSF);
    }
  }
  __syncthreads();
  // LN write: packed bf16, coalesced
  float w0 = lnw[lane * 2], w1 = lnw[lane * 2 + 1];
  float b0 = lnb[lane * 2], b1 = lnb[lane * 2 + 1];
  for (int it = 0; it < 32; ++it) {
    int row = it * 4 + wid;
    float mu = mu_s[row], rr = rs_s[row];
    float v0 = bf2f(Vt[row][lane * 2]);
    float v1 = bf2f(Vt[row][lane * 2 + 1]);
    unsigned lo = (unsigned short)f2bf((v0 - mu) * rr * w0 + b0);
    unsigned hi = (unsigned short)f2bf((v1 - mu) * rr * w1 + b1);
    tnb[(size_t)(m0 + row) * 64 + lane] = lo | (hi << 16);
  }
}

// ---------------- patch-embed bf16 MFMA GEMM ----------------
__global__ __launch_bounds__(256) void gemm_bf16_patch(
    const float* __restrict__ X, const float* __restrict__ B,
    const float* __restrict__ bias, float* __restrict__ C) {
  __shared__ short As[128][40];
  __shared__ short Bs[128][40];
  const int tid = threadIdx.x;
  const int lane = tid & 63, wid = tid >> 6;
  const int wm = wid >> 1, wn = wid & 1;
  const int m0 = blockIdx.x * 128;
  const int r = tid >> 1, hf = tid & 1;
  const int lr = lane & 15, lk = (lane >> 4) * 8;
  const int m = m0 + r;
  const int bb = m >> 8, px = (m >> 4) & 15, py = m & 15;
  f32x4 acc[4][4] = {};
  for (int k0 = 0; k0 < 768; k0 += 32) {
    int k = k0 + hf * 16;
    int c = k >> 8, dx = (k >> 4) & 15;
    {
      const float* ap = X + (((size_t)(bb * 3 + c) * 256 + px * 16 + dx) * 256 + py * 16);
      float4 v0 = *(const float4*)(ap + 0);
      float4 v1 = *(const float4*)(ap + 4);
      float4 v2 = *(const float4*)(ap + 8);
      float4 v3 = *(const float4*)(ap + 12);
      short8 s0, s1;
      s0[0] = f2bf(v0.x); s0[1] = f2bf(v0.y); s0[2] = f2bf(v0.z); s0[3] = f2bf(v0.w);
      s0[4] = f2bf(v1.x); s0[5] = f2bf(v1.y); s0[6] = f2bf(v1.z); s0[7] = f2bf(v1.w);
      s1[0] = f2bf(v2.x); s1[1] = f2bf(v2.y); s1[2] = f2bf(v2.z); s1[3] = f2bf(v2.w);
      s1[4] = f2bf(v3.x); s1[5] = f2bf(v3.y); s1[6] = f2bf(v3.z); s1[7] = f2bf(v3.w);
      *(short8*)&As[r][hf * 16] = s0;
      *(short8*)&As[r][hf * 16 + 8] = s1;
    }
    {
      const float* bp = B + (size_t)r * 768 + k;
      float4 v0 = *(const float4*)(bp + 0);
      float4 v1 = *(const float4*)(bp + 4);
      float4 v2 = *(const float4*)(bp + 8);
      float4 v3 = *(const float4*)(bp + 12);
      short8 s0, s1;
      s0[0] = f2bf(v0.x); s0[1] = f2bf(v0.y); s0[2] = f2bf(v0.z); s0[3] = f2bf(v0.w);
      s0[4] = f2bf(v1.x); s0[5] = f2bf(v1.y); s0[6] = f2bf(v1.z); s0[7] = f2bf(v1.w);
      s1[0] = f2bf(v2.x); s1[1] = f2bf(v2.y); s1[2] = f2bf(v2.z); s1[3] = f2bf(v2.w);
      s1[4] = f2bf(v3.x); s1[5] = f2bf(v3.y); s1[6] = f2bf(v3.z); s1[7] = f2bf(v3.w);
      *(short8*)&Bs[r][hf * 16] = s0;
      *(short8*)&Bs[r][hf * 16 + 8] = s1;
    }
    __syncthreads();
    short8 af[4], bfr[4];
#pragma unroll
    for (int mi = 0; mi < 4; ++mi) af[mi] = *(const short8*)&As[wm * 64 + mi * 16 + lr][lk];
#pragma unroll
    for (int ni = 0; ni < 4; ++ni) bfr[ni] = *(const short8*)&Bs[wn * 64 + ni * 16 + lr][lk];
#pragma unroll
    for (int mi = 0; mi < 4; ++mi)
#pragma unroll
      for (int ni = 0; ni < 4; ++ni)
        acc[mi][ni] = __builtin_amdgcn_mfma_f32_16x16x32_bf16(af[mi], bfr[ni], acc[mi][ni], 0, 0, 0);
    __syncthreads();
  }
#pragma unroll
  for (int mi = 0; mi < 4; ++mi) {
#pragma unroll
    for (int ni = 0; ni < 4; ++ni) {
      int row0 = m0 + wm * 64 + mi * 16 + (lane >> 4) * 4;
      int col = wn * 64 + ni * 16 + (lane & 15);
#pragma unroll
      for (int j = 0; j < 4; ++j)
        C[(size_t)(row0 + j) * 128 + col] = acc[mi][ni][j] + bias[col];
    }
  }
}

// ---------------- fused pe-LN (fp32, in place) + block-0 LN (bf16 out) ----------------
__global__ __launch_bounds__(256) void ln_pe0_kernel(
    float* t, unsigned* out,
    const float* __restrict__ pe_w, const float* __restrict__ pe_b,
    const float* __restrict__ l0w, const float* __restrict__ l0b) {
  int wid = threadIdx.x >> 6, lane = threadIdx.x & 63;
  size_t token = (size_t)blockIdx.x * 4 + wid;
  float* p = t + token * 128;
  float2 v = *(const float2*)(p + lane * 2);
  // pe-LN
  float s = v.x + v.y;
#pragma unroll
  for (int off = 1; off < 64; off <<= 1) s += __shfl_xor(s, off);
  float mu = s * (1.f / 128.f);
  float dx = v.x - mu, dy = v.y - mu;
  float vs = dx * dx + dy * dy;
#pragma unroll
  for (int off = 1; off < 64; off <<= 1) vs += __shfl_xor(vs, off);
  float r = rsqrtf(vs * (1.f / 128.f) + EPSF);
  float t0 = dx * r * pe_w[lane * 2 + 0] + pe_b[lane * 2 + 0];
  float t1 = dy * r * pe_w[lane * 2 + 1] + pe_b[lane * 2 + 1];
  *(float2*)(p + lane * 2) = make_float2(t0, t1);
  // block-0 LN on (t0, t1)
  float s2 = t0 + t1;
#pragma unroll
  for (int off = 1; off < 64; off <<= 1) s2 += __shfl_xor(s2, off);
  float mu2 = s2 * (1.f / 128.f);
  float d0 = t0 - mu2, d1 = t1 - mu2;
  float vs2 = d0 * d0 + d1 * d1;
#pragma unroll
  for (int off = 1; off < 64; off <<= 1) vs2 += __shfl_xor(vs2, off);
  float r2 = rsqrtf(vs2 * (1.f / 128.f) + EPSF);
  unsigned lo = (unsigned short)f2bf(d0 * r2 * l0w[lane * 2 + 0] + l0b[lane * 2 + 0]);
  unsigned hi = (unsigned short)f2bf(d1 * r2 * l0w[lane * 2 + 1] + l0b[lane * 2 + 1]);
  out[token * 64 + lane] = lo | (hi << 16);
}

// ---------------- packed: causal conv1d+SiLU (blocks 0..24575) | dt (blocks 24576..26623) ----------------
__global__ __launch_bounds__(256) void conv_dt_kernel(
    const unsigned short* __restrict__ zx, const float* __restrict__ cw,
    const float* __restrict__ cb, unsigned short* __restrict__ xbc,
    const float* __restrict__ dtraw, const float* __restrict__ dtb,
    const float* __restrict__ A_log, float* __restrict__ dtv, float* __restrict__ ldAv) {
  if (blockIdx.x < 24576) {
    int gid = blockIdx.x * 256 + threadIdx.x;  // T*96
    int token = gid / 96;
    int c4 = (gid - token * 96) * 4;
    int l = token & 255;
    const unsigned short* base = zx + (size_t)token * DIN + DI + c4;
    ushort4 z4 = make_ushort4(0, 0, 0, 0);
    ushort4 u0 = (l >= 3) ? *(const ushort4*)(base - 3 * DIN) : z4;
    ushort4 u1 = (l >= 2) ? *(const ushort4*)(base - 2 * DIN) : z4;
    ushort4 u2 = (l >= 1) ? *(const ushort4*)(base - 1 * DIN) : z4;
    ushort4 u3 = *(const ushort4*)(base);
    float4 w0 = *(const float4*)(cw + (c4 + 0) * 4);
    float4 w1 = *(const float4*)(cw + (c4 + 1) * 4);
    float4 w2 = *(const float4*)(cw + (c4 + 2) * 4);
    float4 w3 = *(const float4*)(cw + (c4 + 3) * 4);
    float4 cbv = *(const float4*)(cb + c4);
    float s0 = cbv.x + w0.x * bf2f(u0.x) + w0.y * bf2f(u1.x) + w0.z * bf2f(u2.x) + w0.w * bf2f(u3.x);
    float s1 = cbv.y + w1.x * bf2f(u0.y) + w1.y * bf2f(u1.y) + w1.z * bf2f(u2.y) + w1.w * bf2f(u3.y);
    float s2 = cbv.z + w2.x * bf2f(u0.z) + w2.y * bf2f(u1.z) + w2.z * bf2f(u2.z) + w2.w * bf2f(u3.z);
    float s3 = cbv.w + w3.x * bf2f(u0.w) + w3.y * bf2f(u1.w) + w3.z * bf2f(u2.w) + w3.w * bf2f(u3.w);
    s0 = s0 / (1.f + expf(-s0));
    s1 = s1 / (1.f + expf(-s1));
    s2 = s2 / (1.f + expf(-s2));
    s3 = s3 / (1.f + expf(-s3));
    unsigned a0 = (unsigned short)f2bf(s0), a1 = (unsigned short)f2bf(s1);
    unsigned a2 = (unsigned short)f2bf(s2), a3 = (unsigned short)f2bf(s3);
    uint2 o = make_uint2(a0 | (a1 << 16), a2 | (a3 << 16));
    *(uint2*)(xbc + (size_t)token * XBC + c4) = o;
  } else {
    int gid = (blockIdx.x - 24576) * 256 + threadIdx.x;  // T*8
    int h = gid & 7;
    float raw = dtraw[gid] + dtb[h];
    float dt = raw > 20.f ? raw : log1pf(expf(raw));
    dtv[gid] = dt;
    ldAv[gid] = -expf(A_log[h]) * dt;
  }
}

// ---------------- chunked SSM scan via MFMA, packed-transpose staging ----------------
__global__ __launch_bounds__(256, 4) void scan_chunk_kernel(
    const unsigned short* __restrict__ xbc,  // [T][384] bf16
    const float* __restrict__ dtv,           // [T][8]
    const float* __restrict__ ldA,           // [T][8]
    const float* __restrict__ Dp,            // [8]
    unsigned short* __restrict__ ysc) {      // [T][256] bf16
  const int b = blockIdx.x & 255, h = blockIdx.x >> 8;
  const int tid = threadIdx.x;
  const int w = tid >> 6, lane = tid & 63;
  const int lr = lane & 15, lj = lane >> 4;
  __shared__ __align__(16) unsigned short Cb[64][72];   // C rows [t][n]; P after phase1
  __shared__ __align__(16) unsigned short Bb[64][72];   // B rows [s][n]
  __shared__ __align__(16) unsigned short BbT[64][72];  // [n][s]
  __shared__ __align__(16) unsigned short xT[32][72];   // [p][t]
  __shared__ __align__(16) unsigned short hbT[32][72];  // h [p][n]
  __shared__ float la[64], dtc[64], wt[64];
  for (int i = tid; i < 32 * 72 / 2; i += 256) ((unsigned*)hbT)[i] = 0;
  f32x4 acc_h[4] = {};   // waves 0,1 own h rows p = w*16 .. w*16+15
  const float dph = Dp[h];
  __syncthreads();

  for (int c = 0; c < 4; ++c) {
    const int tok0 = b * 256 + c * 64;
    if (w == 0) {
      float v = ldA[(size_t)(tok0 + lane) * 8 + h];
#pragma unroll
      for (int off = 1; off < 64; off <<= 1) {
        float u = __shfl_up(v, off);
        if (lane >= off) v += u;
      }
      la[lane] = v;
      dtc[lane] = dtv[(size_t)(tok0 + lane) * 8 + h];
    }
    for (int it = tid; it < 320; it += 256) {
      if (it < 64) {
        int pq = it & 3, tq = it >> 2;
        int t0 = tq * 4, p0 = pq * 8;
        const unsigned short* r0 = xbc + (size_t)(tok0 + t0) * XBC + h * 32 + p0;
        short8 a0 = *(const short8*)(r0);
        short8 a1 = *(const short8*)(r0 + XBC);
        short8 a2 = *(const short8*)(r0 + 2 * XBC);
        short8 a3 = *(const short8*)(r0 + 3 * XBC);
#pragma unroll
        for (int j = 0; j < 8; ++j) {
          ushort4 v;
          v.x = (unsigned short)a0[j]; v.y = (unsigned short)a1[j];
          v.z = (unsigned short)a2[j]; v.w = (unsigned short)a3[j];
          *(ushort4*)&xT[p0 + j][t0] = v;
        }
      } else if (it < 192) {
        int id = it - 64;
        int nq = id & 7, tq = id >> 3;
        int t0 = tq * 4, n0 = nq * 8;
        const unsigned short* r0 = xbc + (size_t)(tok0 + t0) * XBC + 256 + n0;
        short8 a0 = *(const short8*)(r0);
        short8 a1 = *(const short8*)(r0 + XBC);
        short8 a2 = *(const short8*)(r0 + 2 * XBC);
        short8 a3 = *(const short8*)(r0 + 3 * XBC);
        *(short8*)&Bb[t0 + 0][n0] = a0;
        *(short8*)&Bb[t0 + 1][n0] = a1;
        *(short8*)&Bb[t0 + 2][n0] = a2;
        *(short8*)&Bb[t0 + 3][n0] = a3;
#pragma unroll
        for (int j = 0; j < 8; ++j) {
          ushort4 v;
          v.x = (unsigned short)a0[j]; v.y = (unsigned short)a1[j];
          v.z = (unsigned short)a2[j]; v.w = (unsigned short)a3[j];
          *(ushort4*)&BbT[n0 + j][t0] = v;
        }
      } else {
        int id = it - 192;
        int nq = id & 7, tq = id >> 3;
        int t0 = tq * 4, n0 = nq * 8;
        const unsigned short* r0 = xbc + (size_t)(tok0 + t0) * XBC + 320 + n0;
        *(short8*)&Cb[t0 + 0][n0] = *(const short8*)(r0);
        *(short8*)&Cb[t0 + 1][n0] = *(const short8*)(r0 + XBC);
        *(short8*)&Cb[t0 + 2][n0] = *(const short8*)(r0 + 2 * XBC);
        *(short8*)&Cb[t0 + 3][n0] = *(const short8*)(r0 + 3 * XBC);
      }
    }
    __syncthreads();   // bar1
    if (w == 3) wt[lane] = __expf(la[63] - la[lane]) * dtc[lane];
    short8 afC0 = *(const short8*)&Cb[w * 16 + lr][lj * 8];
    short8 afC1 = *(const short8*)&Cb[w * 16 + lr][32 + lj * 8];
    f32x4 acc_s[4] = {};
#pragma unroll
    for (int ni = 0; ni < 4; ++ni) {
      short8 bf0 = *(const short8*)&Bb[ni * 16 + lr][lj * 8];
      short8 bf1 = *(const short8*)&Bb[ni * 16 + lr][32 + lj * 8];
      acc_s[ni] = __builtin_amdgcn_mfma_f32_16x16x32_bf16(afC0, bf0, acc_s[ni], 0, 0, 0);
      acc_s[ni] = __builtin_amdgcn_mfma_f32_16x16x32_bf16(afC1, bf1, acc_s[ni], 0, 0, 0);
    }
    f32x4 acc_y[2] = {};
#pragma unroll
    for (int ni = 0; ni < 2; ++ni) {
      short8 hf0 = *(const short8*)&hbT[ni * 16 + lr][lj * 8];
      short8 hf1 = *(const short8*)&hbT[ni * 16 + lr][32 + lj * 8];
      acc_y[ni] = __builtin_amdgcn_mfma_f32_16x16x32_bf16(afC0, hf0, acc_y[ni], 0, 0, 0);
      acc_y[ni] = __builtin_amdgcn_mfma_f32_16x16x32_bf16(afC1, hf1, acc_y[ni], 0, 0, 0);
    }
#pragma unroll
    for (int j = 0; j < 4; ++j) {
      float at = __expf(la[w * 16 + lj * 4 + j]);
      acc_y[0][j] *= at;
      acc_y[1][j] *= at;
    }
    __syncthreads();   // bar2
#pragma unroll
    for (int ni = 0; ni < 4; ++ni) {
      int s = ni * 16 + lr;
      float las = la[s], dts = dtc[s];
#pragma unroll
      for (int j = 0; j < 4; ++j) {
        int t = w * 16 + lj * 4 + j;
        float pv = 0.f;
        if (s <= t) pv = acc_s[ni][j] * __expf(la[t] - las) * dts;
        Cb[t][s] = (unsigned short)f2bf(pv);
      }
    }
    __syncthreads();   // bar3
    {
      short8 afP0 = *(const short8*)&Cb[w * 16 + lr][lj * 8];
      short8 afP1 = *(const short8*)&Cb[w * 16 + lr][32 + lj * 8];
#pragma unroll
      for (int ni = 0; ni < 2; ++ni) {
        short8 xf0 = *(const short8*)&xT[ni * 16 + lr][lj * 8];
        short8 xf1 = *(const short8*)&xT[ni * 16 + lr][32 + lj * 8];
        acc_y[ni] = __builtin_amdgcn_mfma_f32_16x16x32_bf16(afP0, xf0, acc_y[ni], 0, 0, 0);
        acc_y[ni] = __builtin_amdgcn_mfma_f32_16x16x32_bf16(afP1, xf1, acc_y[ni], 0, 0, 0);
      }
    }
    if (w < 2) {
      float aend = __expf(la[63]);
#pragma unroll
      for (int ni = 0; ni < 4; ++ni)
#pragma unroll
        for (int j = 0; j < 4; ++j) acc_h[ni][j] *= aend;
#pragma unroll
      for (int kk = 0; kk < 2; ++kk) {
        short8 xv = *(const short8*)&xT[w * 16 + lr][kk * 32 + lj * 8];
        short8 axf;
#pragma unroll
        for (int j = 0; j < 8; ++j)
          axf[j] = f2bf(bf2f((unsigned short)xv[j]) * wt[kk * 32 + lj * 8 + j]);
#pragma unroll
        for (int ni = 0; ni < 4; ++ni) {
          short8 bw = *(const short8*)&BbT[ni * 16 + lr][kk * 32 + lj * 8];
          acc_h[ni] = __builtin_amdgcn_mfma_f32_16x16x32_bf16(axf, bw, acc_h[ni], 0, 0, 0);
        }
      }
    }
#pragma unroll
    for (int ni = 0; ni < 2; ++ni) {
#pragma unroll
      for (int j = 0; j < 4; ++j) {
        int t = w * 16 + lj * 4 + j;
        int p = ni * 16 + lr;
        float yv = acc_y[ni][j] + dph * bf2f(xT[p][t]);
        ysc[(size_t)(tok0 + t) * DI + h * 32 + p] = (unsigned short)f2bf(yv);
      }
    }
    if (w < 2) {
#pragma unroll
      for (int ni = 0; ni < 4; ++ni)
#pragma unroll
        for (int j = 0; j < 4; ++j)
          hbT[w * 16 + lj * 4 + j][ni * 16 + lr] = (unsigned short)f2bf(acc_h[ni][j]);
    }
    __syncthreads();   // bar4
  }
}

// ---------------- y = rmsnorm(y * silu(z)) * nw -> bf16 (y bf16 in) ----------------
__global__ __launch_bounds__(256) void gate_rms_kernel(
    const unsigned short* __restrict__ ysc, const unsigned short* __restrict__ zx,
    const float* __restrict__ nw, unsigned short* __restrict__ yout) {
  int wid = threadIdx.x >> 6, lane = threadIdx.x & 63;
  size_t token = (size_t)blockIdx.x * 4 + wid;
  ushort4 yu = *(const ushort4*)(ysc + token * DI + lane * 4);
  ushort4 zu = *(const ushort4*)(zx + token * DIN + lane * 4);
  float y0 = bf2f(yu.x), y1 = bf2f(yu.y), y2 = bf2f(yu.z), y3 = bf2f(yu.w);
  float z0 = bf2f(zu.x), z1 = bf2f(zu.y), z2 = bf2f(zu.z), z3 = bf2f(zu.w);
  float g0 = y0 * (z0 / (1.f + expf(-z0)));
  float g1 = y1 * (z1 / (1.f + expf(-z1)));
  float g2 = y2 * (z2 / (1.f + expf(-z2)));
  float g3 = y3 * (z3 / (1.f + expf(-z3)));
  float ss = g0 * g0 + g1 * g1 + g2 * g2 + g3 * g3;
#pragma unroll
  for (int off = 1; off < 64; off <<= 1) ss += __shfl_xor(ss, off);
  float r = rsqrtf(ss * (1.f / 256.f) + EPSF);
  unsigned w0 = (unsigned short)f2bf(g0 * r * nw[lane * 4 + 0]);
  unsigned w1 = (unsigned short)f2bf(g1 * r * nw[lane * 4 + 1]);
  unsigned w2 = (unsigned short)f2bf(g2 * r * nw[lane * 4 + 2]);
  unsigned w3 = (unsigned short)f2bf(g3 * r * nw[lane * 4 + 3]);
  uint2 packed = make_uint2(w0 | (w1 << 16), w2 | (w3 << 16));
  *(uint2*)(yout + token * DI + lane * 4) = packed;
}

// ---------------- head: column mean + matmul + L2 normalize (fused) ----------------
__global__ __launch_bounds__(128) void head_kernel(
    const unsigned short* __restrict__ tn, const float* __restrict__ hw,
    const float* __restrict__ hb, float* __restrict__ out) {
  __shared__ float tm[128];
  __shared__ float red[2];
  int b = blockIdx.x, o = threadIdx.x;
  // column mean over L
  {
    const unsigned short* p = tn + (size_t)b * 256 * 128 + o;
    float acc = 0.f;
    for (int l = 0; l < 256; ++l) acc += bf2f(p[l * 128]);
    tm[o] = acc * (1.f / 256.f);
  }
  __syncthreads();
  float acc = hb[o];
  for (int e = 0; e < 128; ++e) acc += tm[e] * hw[o * 128 + e];
  float ss = acc * acc;
#pragma unroll
  for (int off = 1; off < 64; off <<= 1) ss += __shfl_xor(ss, off);
  if ((o & 63) == 0) red[o >> 6] = ss;
  __syncthreads();
  float nrm = fmaxf(sqrtf(red[0] + red[1]), 1e-12f);
  out[b * 128 + o] = acc / nrm;
}

extern "C" void kernel_launch(void* const* d_in, const int* in_sizes, int n_in,
                              void* d_out, int out_size, void* d_ws, size_t ws_size,
                              hipStream_t stream) {
  const float* x      = (const float*)d_in[0];
  const float* conv_w = (const float*)d_in[1];
  const float* conv_b = (const float*)d_in[2];
  const float* pe_w   = (const float*)d_in[3];
  const float* pe_b   = (const float*)d_in[4];
  const float* ln_w   = (const float*)d_in[5];
  const float* ln_b   = (const float*)d_in[6];
  const float* in_w   = (const float*)d_in[7];
  const float* c1w    = (const float*)d_in[8];
  const float* c1b    = (const float*)d_in[9];
  const float* dtb    = (const float*)d_in[10];
  const float* A_log  = (const float*)d_in[11];
  const float* Dp     = (const float*)d_in[12];
  const float* nw     = (const float*)d_in[13];
  const float* ow     = (const float*)d_in[14];
  const float* fn_w   = (const float*)d_in[15];
  const float* fn_b   = (const float*)d_in[16];
  const float* hw     = (const float*)d_in[17];
  const float* hb     = (const float*)d_in[18];
  float* out = (float*)d_out;

  const size_t T = TTOK;
  char* w8 = (char*)d_ws;
  float*          t_buf = (float*)w8;            w8 += T * 128 * 4;   // residual fp32
  unsigned*       tnb   = (unsigned*)w8;         w8 += T * 128 * 2;   // ln out bf16
  unsigned short* zx    = (unsigned short*)w8;   w8 += T * (size_t)DIN * 2; // in-proj bf16
  unsigned short* xbc   = (unsigned short*)w8;   w8 += T * (size_t)XBC * 2; // conv out bf16
  float*          dtraw = (float*)w8;            w8 += T * 8 * 4;
  float*          dtv   = (float*)w8;            w8 += T * 8 * 4;
  float*          ldAv  = (float*)w8;            w8 += T * 8 * 4;
  unsigned short* ysc   = (unsigned short*)w8;   w8 += T * (size_t)DI * 2;  // scan out bf16
  unsigned short* ybb   = (unsigned short*)w8;   w8 += T * (size_t)DI * 2;  // gated bf16
  unsigned short* in_wb = (unsigned short*)w8;   w8 += (size_t)NL * DIN * EE * 2;
  unsigned short* owb   = (unsigned short*)w8;   w8 += (size_t)NL * EE * DI * 2;
  if ((size_t)(w8 - (char*)d_ws) > ws_size) return;  // workspace too small

  // one-shot weight conversion (NL*DIN*EE = 331776 = 1296*256)
  cvt_w_kernel<<<1296, 256, 0, stream>>>(in_w, ow, in_wb, owb);

  // patch embed + bias, then fused pe-LN (fp32) + block-0 LN (bf16)
  gemm_bf16_patch<<<dim3(512, 1), 256, 0, stream>>>(x, conv_w, conv_b, t_buf);
  ln_pe0_kernel<<<16384, 256, 0, stream>>>(t_buf, tnb, pe_w, pe_b, ln_w, ln_b);

  for (int i = 0; i < NL; ++i) {
    gemm_in_proj<<<dim3(512, 6), 256, 0, stream>>>(
        (const unsigned short*)tnb, in_wb + (size_t)i * DIN * EE, zx, dtraw, TTOK, DIN, EE);
    conv_dt_kernel<<<26624, 256, 0, stream>>>(
        zx, c1w + (size_t)i * XBC * DC, c1b + (size_t)i * XBC, xbc,
        dtraw, dtb + i * HH, A_log + i * HH, dtv, ldAv);
    scan_chunk_kernel<<<2048, 256, 0, stream>>>(xbc, dtv, ldAv, Dp + i * HH, ysc);
    gate_rms_kernel<<<16384, 256, 0, stream>>>(ysc, zx, nw + i * DI, ybb);
    const float* nlw = (i < NL - 1) ? (ln_w + (i + 1) * 128) : fn_w;
    const float* nlb = (i < NL - 1) ? (ln_b + (i + 1) * 128) : fn_b;
    gemm_out_ln<<<512, 256, 0, stream>>>(
        ybb, owb + (size_t)i * EE * DI, t_buf, nlw, nlb, tnb);
  }

  // tnb holds final-LN output (fused in last gemm_out_ln)
  head_kernel<<<256, 128, 0, stream>>>((const unsigned short*)tnb, hw, hb, out);
}

// Round 15
// 893.162 us; speedup vs baseline: 1.0782x; 1.0039x over previous
//
#include <hip/hip_runtime.h>
#include <math.h>

// ---------------- constants ----------------
#define EE 128
#define DI 256
#define HH 8
#define PP 32
#define NN 64
#define DC 4
#define XBC 384
#define DIN 648
#define NL 4
#define LSEQ 256
#define BB 256
#define TTOK (BB * LSEQ)   // 65536 tokens
#define EPSF 1e-5f

typedef __attribute__((ext_vector_type(8))) short short8;
typedef __attribute__((ext_vector_type(4))) float f32x4;

__device__ inline short f2bf(float f) {
  unsigned u = __builtin_bit_cast(unsigned, f);
  u += 0x7fff + ((u >> 16) & 1);   // RNE
  return (short)(u >> 16);
}
__device__ inline float bf2f(unsigned short u) {
  unsigned x = ((unsigned)u) << 16;
  return __builtin_bit_cast(float, x);
}

// ---------------- one-shot weight conversion fp32 -> bf16 ----------------
__global__ __launch_bounds__(256) void cvt_w_kernel(
    const float* __restrict__ in_w, const float* __restrict__ ow,
    unsigned short* __restrict__ in_wb, unsigned short* __restrict__ owb) {
  int i = blockIdx.x * 256 + threadIdx.x;   // grid covers NL*DIN*EE = 331776
  in_wb[i] = (unsigned short)f2bf(in_w[i]);
  if (i < NL * EE * DI) owb[i] = (unsigned short)f2bf(ow[i]);
}

// ---------------- in-proj GEMM: bf16 A,B; bf16 out (LDS-coalesced) + fp32 dt side-channel ----------------
// grid = dim3(6, 512): n-tile fastest so the 6 blocks sharing one A-panel are
// dispatch-adjacent (A-panel stays L2-warm; tnb re-read 6x -> ~1x from HBM/L3).
__global__ __launch_bounds__(256) void gemm_in_proj(
    const unsigned short* __restrict__ A, const unsigned short* __restrict__ B,
    unsigned short* __restrict__ Czx, float* __restrict__ dtraw,
    int M, int N, int K) {
  __shared__ __align__(16) unsigned short smem[128 * 136];
  short (*As)[40] = (short(*)[40])smem;
  short (*Bs)[40] = (short(*)[40])(smem + 128 * 40);
  const int tid = threadIdx.x;
  const int lane = tid & 63, wid = tid >> 6;
  const int wm = wid >> 1, wn = wid & 1;
  const int m0 = blockIdx.y * 128, n0 = blockIdx.x * 128;
  const int r = tid >> 1, hf = tid & 1;
  const int lr = lane & 15, lk = (lane >> 4) * 8;
  f32x4 acc[4][4] = {};
  for (int k0 = 0; k0 < K; k0 += 32) {
    {
      const unsigned short* ap = A + (size_t)(m0 + r) * K + k0 + hf * 16;
      *(short8*)&As[r][hf * 16] = *(const short8*)(ap);
      *(short8*)&As[r][hf * 16 + 8] = *(const short8*)(ap + 8);
    }
    {
      short8 s0 = {}, s1 = {};
      if (n0 + r < N) {
        const unsigned short* bp = B + (size_t)(n0 + r) * K + k0 + hf * 16;
        s0 = *(const short8*)(bp);
        s1 = *(const short8*)(bp + 8);
      }
      *(short8*)&Bs[r][hf * 16] = s0;
      *(short8*)&Bs[r][hf * 16 + 8] = s1;
    }
    __syncthreads();
    short8 af[4], bfr[4];
#pragma unroll
    for (int mi = 0; mi < 4; ++mi) af[mi] = *(const short8*)&As[wm * 64 + mi * 16 + lr][lk];
#pragma unroll
    for (int ni = 0; ni < 4; ++ni) bfr[ni] = *(const short8*)&Bs[wn * 64 + ni * 16 + lr][lk];
#pragma unroll
    for (int mi = 0; mi < 4; ++mi)
#pragma unroll
      for (int ni = 0; ni < 4; ++ni)
        acc[mi][ni] = __builtin_amdgcn_mfma_f32_16x16x32_bf16(af[mi], bfr[ni], acc[mi][ni], 0, 0, 0);
    __syncthreads();
  }
  // epilogue: bf16 tile -> LDS, then coalesced 16B stores
  {
    unsigned short (*Vt)[136] = (unsigned short(*)[136])smem;
#pragma unroll
    for (int mi = 0; mi < 4; ++mi) {
#pragma unroll
      for (int ni = 0; ni < 4; ++ni) {
        int row0 = wm * 64 + mi * 16 + (lane >> 4) * 4;
        int col = wn * 64 + ni * 16 + lr;
#pragma unroll
        for (int j = 0; j < 4; ++j)
          Vt[row0 + j][col] = (unsigned short)f2bf(acc[mi][ni][j]);
      }
    }
    // dt raw side-channel: only tile n0==640, cols 640..647 (wn==0, ni==0, lr<8)
    if (n0 == 640 && wn == 0 && lr < 8) {
#pragma unroll
      for (int mi = 0; mi < 4; ++mi) {
        int row0 = m0 + wm * 64 + mi * 16 + (lane >> 4) * 4;
#pragma unroll
        for (int j = 0; j < 4; ++j)
          dtraw[(size_t)(row0 + j) * 8 + lr] = acc[mi][0][j];
      }
    }
    __syncthreads();
    const int row = tid >> 4, cs = (tid & 15) * 8;
#pragma unroll
    for (int it = 0; it < 8; ++it) {
      int rr2 = it * 16 + row;
      if (n0 + cs < N)
        *(uint4*)(Czx + (size_t)(m0 + rr2) * DIN + n0 + cs) = *(const uint4*)&Vt[rr2][cs];
    }
  }
}

// ---------------- out-proj + residual + fused next-LayerNorm (128-token tile) ----------------
__global__ __launch_bounds__(256) void gemm_out_ln(
    const unsigned short* __restrict__ A, const unsigned short* __restrict__ B,
    float* __restrict__ tres, const float* __restrict__ lnw,
    const float* __restrict__ lnb, unsigned* __restrict__ tnb) {
  __shared__ short As[128][40];
  __shared__ short Bs[128][40];
  __shared__ unsigned short Vt[128][136];
  __shared__ float mu_s[128], rs_s[128];
  const int tid = threadIdx.x;
  const int lane = tid & 63, wid = tid >> 6;
  const int wm = wid >> 1, wn = wid & 1;
  const int m0 = blockIdx.x * 128;
  const int r = tid >> 1, hf = tid & 1;
  const int lr = lane & 15, lk = (lane >> 4) * 8;
  f32x4 acc[4][4] = {};
  for (int k0 = 0; k0 < 256; k0 += 32) {
    {
      const unsigned short* ap = A + (size_t)(m0 + r) * 256 + k0 + hf * 16;
      *(short8*)&As[r][hf * 16] = *(const short8*)(ap);
      *(short8*)&As[r][hf * 16 + 8] = *(const short8*)(ap + 8);
    }
    {
      const unsigned short* bp = B + (size_t)r * 256 + k0 + hf * 16;
      *(short8*)&Bs[r][hf * 16] = *(const short8*)(bp);
      *(short8*)&Bs[r][hf * 16 + 8] = *(const short8*)(bp + 8);
    }
    __syncthreads();
    short8 af[4], bfr[4];
#pragma unroll
    for (int mi = 0; mi < 4; ++mi) af[mi] = *(const short8*)&As[wm * 64 + mi * 16 + lr][lk];
#pragma unroll
    for (int ni = 0; ni < 4; ++ni) bfr[ni] = *(const short8*)&Bs[wn * 64 + ni * 16 + lr][lk];
#pragma unroll
    for (int mi = 0; mi < 4; ++mi)
#pragma unroll
      for (int ni = 0; ni < 4; ++ni)
        acc[mi][ni] = __builtin_amdgcn_mfma_f32_16x16x32_bf16(af[mi], bfr[ni], acc[mi][ni], 0, 0, 0);
    __syncthreads();
  }
  // epilogue: residual add, fp32 store, bf16 LDS tile
#pragma unroll
  for (int mi = 0; mi < 4; ++mi) {
#pragma unroll
    for (int ni = 0; ni < 4; ++ni) {
      int row0 = wm * 64 + mi * 16 + (lane >> 4) * 4;
      int col = wn * 64 + ni * 16 + lr;
#pragma unroll
      for (int j = 0; j < 4; ++j) {
        int row = row0 + j;
        size_t idx = (size_t)(m0 + row) * 128 + col;
        float v = acc[mi][ni][j] + tres[idx];
        tres[idx] = v;
        Vt[row][col] = (unsigned short)f2bf(v);
      }
    }
  }
  __syncthreads();
  // per-row stats (2 threads per row)
  {
    int row = tid >> 1;
    float s = 0.f, ss = 0.f;
#pragma unroll
    for (int kk = 0; kk < 8; ++kk) {
      short8 vv = *(const short8*)&Vt[row][hf * 64 + kk * 8];
#pragma unroll
      for (int j = 0; j < 8; ++j) {
        float f = bf2f((unsigned short)vv[j]);
        s += f; ss += f * f;
      }
    }
    s += __shfl_xor(s, 1);
    ss += __shfl_xor(ss, 1);
    if (hf == 0) {
      float mu = s * (1.f / 128.f);
      mu_s[row] = mu;
      rs_s[row] = rsqrtf(ss * (1.f / 128.f) - mu * mu + EPSF);
    }
  }
  __syncthreads();
  // LN write: packed bf16, coalesced
  float w0 = lnw[lane * 2], w1 = lnw[lane * 2 + 1];
  float b0 = lnb[lane * 2], b1 = lnb[lane * 2 + 1];
  for (int it = 0; it < 32; ++it) {
    int row = it * 4 + wid;
    float mu = mu_s[row], rr = rs_s[row];
    float v0 = bf2f(Vt[row][lane * 2]);
    float v1 = bf2f(Vt[row][lane * 2 + 1]);
    unsigned lo = (unsigned short)f2bf((v0 - mu) * rr * w0 + b0);
    unsigned hi = (unsigned short)f2bf((v1 - mu) * rr * w1 + b1);
    tnb[(size_t)(m0 + row) * 64 + lane] = lo | (hi << 16);
  }
}

// ---------------- patch-embed bf16 MFMA GEMM ----------------
__global__ __launch_bounds__(256) void gemm_bf16_patch(
    const float* __restrict__ X, const float* __restrict__ B,
    const float* __restrict__ bias, float* __restrict__ C) {
  __shared__ short As[128][40];
  __shared__ short Bs[128][40];
  const int tid = threadIdx.x;
  const int lane = tid & 63, wid = tid >> 6;
  const int wm = wid >> 1, wn = wid & 1;
  const int m0 = blockIdx.x * 128;
  const int r = tid >> 1, hf = tid & 1;
  const int lr = lane & 15, lk = (lane >> 4) * 8;
  const int m = m0 + r;
  const int bb = m >> 8, px = (m >> 4) & 15, py = m & 15;
  f32x4 acc[4][4] = {};
  for (int k0 = 0; k0 < 768; k0 += 32) {
    int k = k0 + hf * 16;
    int c = k >> 8, dx = (k >> 4) & 15;
    {
      const float* ap = X + (((size_t)(bb * 3 + c) * 256 + px * 16 + dx) * 256 + py * 16);
      float4 v0 = *(const float4*)(ap + 0);
      float4 v1 = *(const float4*)(ap + 4);
      float4 v2 = *(const float4*)(ap + 8);
      float4 v3 = *(const float4*)(ap + 12);
      short8 s0, s1;
      s0[0] = f2bf(v0.x); s0[1] = f2bf(v0.y); s0[2] = f2bf(v0.z); s0[3] = f2bf(v0.w);
      s0[4] = f2bf(v1.x); s0[5] = f2bf(v1.y); s0[6] = f2bf(v1.z); s0[7] = f2bf(v1.w);
      s1[0] = f2bf(v2.x); s1[1] = f2bf(v2.y); s1[2] = f2bf(v2.z); s1[3] = f2bf(v2.w);
      s1[4] = f2bf(v3.x); s1[5] = f2bf(v3.y); s1[6] = f2bf(v3.z); s1[7] = f2bf(v3.w);
      *(short8*)&As[r][hf * 16] = s0;
      *(short8*)&As[r][hf * 16 + 8] = s1;
    }
    {
      const float* bp = B + (size_t)r * 768 + k;
      float4 v0 = *(const float4*)(bp + 0);
      float4 v1 = *(const float4*)(bp + 4);
      float4 v2 = *(const float4*)(bp + 8);
      float4 v3 = *(const float4*)(bp + 12);
      short8 s0, s1;
      s0[0] = f2bf(v0.x); s0[1] = f2bf(v0.y); s0[2] = f2bf(v0.z); s0[3] = f2bf(v0.w);
      s0[4] = f2bf(v1.x); s0[5] = f2bf(v1.y); s0[6] = f2bf(v1.z); s0[7] = f2bf(v1.w);
      s1[0] = f2bf(v2.x); s1[1] = f2bf(v2.y); s1[2] = f2bf(v2.z); s1[3] = f2bf(v2.w);
      s1[4] = f2bf(v3.x); s1[5] = f2bf(v3.y); s1[6] = f2bf(v3.z); s1[7] = f2bf(v3.w);
      *(short8*)&Bs[r][hf * 16] = s0;
      *(short8*)&Bs[r][hf * 16 + 8] = s1;
    }
    __syncthreads();
    short8 af[4], bfr[4];
#pragma unroll
    for (int mi = 0; mi < 4; ++mi) af[mi] = *(const short8*)&As[wm * 64 + mi * 16 + lr][lk];
#pragma unroll
    for (int ni = 0; ni < 4; ++ni) bfr[ni] = *(const short8*)&Bs[wn * 64 + ni * 16 + lr][lk];
#pragma unroll
    for (int mi = 0; mi < 4; ++mi)
#pragma unroll
      for (int ni = 0; ni < 4; ++ni)
        acc[mi][ni] = __builtin_amdgcn_mfma_f32_16x16x32_bf16(af[mi], bfr[ni], acc[mi][ni], 0, 0, 0);
    __syncthreads();
  }
#pragma unroll
  for (int mi = 0; mi < 4; ++mi) {
#pragma unroll
    for (int ni = 0; ni < 4; ++ni) {
      int row0 = m0 + wm * 64 + mi * 16 + (lane >> 4) * 4;
      int col = wn * 64 + ni * 16 + (lane & 15);
#pragma unroll
      for (int j = 0; j < 4; ++j)
        C[(size_t)(row0 + j) * 128 + col] = acc[mi][ni][j] + bias[col];
    }
  }
}

// ---------------- fused pe-LN (fp32, in place) + block-0 LN (bf16 out) ----------------
__global__ __launch_bounds__(256) void ln_pe0_kernel(
    float* t, unsigned* out,
    const float* __restrict__ pe_w, const float* __restrict__ pe_b,
    const float* __restrict__ l0w, const float* __restrict__ l0b) {
  int wid = threadIdx.x >> 6, lane = threadIdx.x & 63;
  size_t token = (size_t)blockIdx.x * 4 + wid;
  float* p = t + token * 128;
  float2 v = *(const float2*)(p + lane * 2);
  // pe-LN
  float s = v.x + v.y;
#pragma unroll
  for (int off = 1; off < 64; off <<= 1) s += __shfl_xor(s, off);
  float mu = s * (1.f / 128.f);
  float dx = v.x - mu, dy = v.y - mu;
  float vs = dx * dx + dy * dy;
#pragma unroll
  for (int off = 1; off < 64; off <<= 1) vs += __shfl_xor(vs, off);
  float r = rsqrtf(vs * (1.f / 128.f) + EPSF);
  float t0 = dx * r * pe_w[lane * 2 + 0] + pe_b[lane * 2 + 0];
  float t1 = dy * r * pe_w[lane * 2 + 1] + pe_b[lane * 2 + 1];
  *(float2*)(p + lane * 2) = make_float2(t0, t1);
  // block-0 LN on (t0, t1)
  float s2 = t0 + t1;
#pragma unroll
  for (int off = 1; off < 64; off <<= 1) s2 += __shfl_xor(s2, off);
  float mu2 = s2 * (1.f / 128.f);
  float d0 = t0 - mu2, d1 = t1 - mu2;
  float vs2 = d0 * d0 + d1 * d1;
#pragma unroll
  for (int off = 1; off < 64; off <<= 1) vs2 += __shfl_xor(vs2, off);
  float r2 = rsqrtf(vs2 * (1.f / 128.f) + EPSF);
  unsigned lo = (unsigned short)f2bf(d0 * r2 * l0w[lane * 2 + 0] + l0b[lane * 2 + 0]);
  unsigned hi = (unsigned short)f2bf(d1 * r2 * l0w[lane * 2 + 1] + l0b[lane * 2 + 1]);
  out[token * 64 + lane] = lo | (hi << 16);
}

// ---------------- packed: causal conv1d+SiLU (blocks 0..24575) | dt (blocks 24576..26623) ----------------
__global__ __launch_bounds__(256) void conv_dt_kernel(
    const unsigned short* __restrict__ zx, const float* __restrict__ cw,
    const float* __restrict__ cb, unsigned short* __restrict__ xbc,
    const float* __restrict__ dtraw, const float* __restrict__ dtb,
    const float* __restrict__ A_log, float* __restrict__ dtv, float* __restrict__ ldAv) {
  if (blockIdx.x < 24576) {
    int gid = blockIdx.x * 256 + threadIdx.x;  // T*96
    int token = gid / 96;
    int c4 = (gid - token * 96) * 4;
    int l = token & 255;
    const unsigned short* base = zx + (size_t)token * DIN + DI + c4;
    ushort4 z4 = make_ushort4(0, 0, 0, 0);
    ushort4 u0 = (l >= 3) ? *(const ushort4*)(base - 3 * DIN) : z4;
    ushort4 u1 = (l >= 2) ? *(const ushort4*)(base - 2 * DIN) : z4;
    ushort4 u2 = (l >= 1) ? *(const ushort4*)(base - 1 * DIN) : z4;
    ushort4 u3 = *(const ushort4*)(base);
    float4 w0 = *(const float4*)(cw + (c4 + 0) * 4);
    float4 w1 = *(const float4*)(cw + (c4 + 1) * 4);
    float4 w2 = *(const float4*)(cw + (c4 + 2) * 4);
    float4 w3 = *(const float4*)(cw + (c4 + 3) * 4);
    float4 cbv = *(const float4*)(cb + c4);
    float s0 = cbv.x + w0.x * bf2f(u0.x) + w0.y * bf2f(u1.x) + w0.z * bf2f(u2.x) + w0.w * bf2f(u3.x);
    float s1 = cbv.y + w1.x * bf2f(u0.y) + w1.y * bf2f(u1.y) + w1.z * bf2f(u2.y) + w1.w * bf2f(u3.y);
    float s2 = cbv.z + w2.x * bf2f(u0.z) + w2.y * bf2f(u1.z) + w2.z * bf2f(u2.z) + w2.w * bf2f(u3.z);
    float s3 = cbv.w + w3.x * bf2f(u0.w) + w3.y * bf2f(u1.w) + w3.z * bf2f(u2.w) + w3.w * bf2f(u3.w);
    s0 = s0 / (1.f + expf(-s0));
    s1 = s1 / (1.f + expf(-s1));
    s2 = s2 / (1.f + expf(-s2));
    s3 = s3 / (1.f + expf(-s3));
    unsigned a0 = (unsigned short)f2bf(s0), a1 = (unsigned short)f2bf(s1);
    unsigned a2 = (unsigned short)f2bf(s2), a3 = (unsigned short)f2bf(s3);
    uint2 o = make_uint2(a0 | (a1 << 16), a2 | (a3 << 16));
    *(uint2*)(xbc + (size_t)token * XBC + c4) = o;
  } else {
    int gid = (blockIdx.x - 24576) * 256 + threadIdx.x;  // T*8
    int h = gid & 7;
    float raw = dtraw[gid] + dtb[h];
    float dt = raw > 20.f ? raw : log1pf(expf(raw));
    dtv[gid] = dt;
    ldAv[gid] = -expf(A_log[h]) * dt;
  }
}

// ---------------- chunked SSM scan via MFMA, packed-transpose staging ----------------
__global__ __launch_bounds__(256, 4) void scan_chunk_kernel(
    const unsigned short* __restrict__ xbc,  // [T][384] bf16
    const float* __restrict__ dtv,           // [T][8]
    const float* __restrict__ ldA,           // [T][8]
    const float* __restrict__ Dp,            // [8]
    unsigned short* __restrict__ ysc) {      // [T][256] bf16
  const int b = blockIdx.x & 255, h = blockIdx.x >> 8;
  const int tid = threadIdx.x;
  const int w = tid >> 6, lane = tid & 63;
  const int lr = lane & 15, lj = lane >> 4;
  __shared__ __align__(16) unsigned short Cb[64][72];   // C rows [t][n]; P after phase1
  __shared__ __align__(16) unsigned short Bb[64][72];   // B rows [s][n]
  __shared__ __align__(16) unsigned short BbT[64][72];  // [n][s]
  __shared__ __align__(16) unsigned short xT[32][72];   // [p][t]
  __shared__ __align__(16) unsigned short hbT[32][72];  // h [p][n]
  __shared__ float la[64], dtc[64], wt[64];
  for (int i = tid; i < 32 * 72 / 2; i += 256) ((unsigned*)hbT)[i] = 0;
  f32x4 acc_h[4] = {};   // waves 0,1 own h rows p = w*16 .. w*16+15
  const float dph = Dp[h];
  __syncthreads();

  for (int c = 0; c < 4; ++c) {
    const int tok0 = b * 256 + c * 64;
    if (w == 0) {
      float v = ldA[(size_t)(tok0 + lane) * 8 + h];
#pragma unroll
      for (int off = 1; off < 64; off <<= 1) {
        float u = __shfl_up(v, off);
        if (lane >= off) v += u;
      }
      la[lane] = v;
      dtc[lane] = dtv[(size_t)(tok0 + lane) * 8 + h];
    }
    for (int it = tid; it < 320; it += 256) {
      if (it < 64) {
        int pq = it & 3, tq = it >> 2;
        int t0 = tq * 4, p0 = pq * 8;
        const unsigned short* r0 = xbc + (size_t)(tok0 + t0) * XBC + h * 32 + p0;
        short8 a0 = *(const short8*)(r0);
        short8 a1 = *(const short8*)(r0 + XBC);
        short8 a2 = *(const short8*)(r0 + 2 * XBC);
        short8 a3 = *(const short8*)(r0 + 3 * XBC);
#pragma unroll
        for (int j = 0; j < 8; ++j) {
          ushort4 v;
          v.x = (unsigned short)a0[j]; v.y = (unsigned short)a1[j];
          v.z = (unsigned short)a2[j]; v.w = (unsigned short)a3[j];
          *(ushort4*)&xT[p0 + j][t0] = v;
        }
      } else if (it < 192) {
        int id = it - 64;
        int nq = id & 7, tq = id >> 3;
        int t0 = tq * 4, n0 = nq * 8;
        const unsigned short* r0 = xbc + (size_t)(tok0 + t0) * XBC + 256 + n0;
        short8 a0 = *(const short8*)(r0);
        short8 a1 = *(const short8*)(r0 + XBC);
        short8 a2 = *(const short8*)(r0 + 2 * XBC);
        short8 a3 = *(const short8*)(r0 + 3 * XBC);
        *(short8*)&Bb[t0 + 0][n0] = a0;
        *(short8*)&Bb[t0 + 1][n0] = a1;
        *(short8*)&Bb[t0 + 2][n0] = a2;
        *(short8*)&Bb[t0 + 3][n0] = a3;
#pragma unroll
        for (int j = 0; j < 8; ++j) {
          ushort4 v;
          v.x = (unsigned short)a0[j]; v.y = (unsigned short)a1[j];
          v.z = (unsigned short)a2[j]; v.w = (unsigned short)a3[j];
          *(ushort4*)&BbT[n0 + j][t0] = v;
        }
      } else {
        int id = it - 192;
        int nq = id & 7, tq = id >> 3;
        int t0 = tq * 4, n0 = nq * 8;
        const unsigned short* r0 = xbc + (size_t)(tok0 + t0) * XBC + 320 + n0;
        *(short8*)&Cb[t0 + 0][n0] = *(const short8*)(r0);
        *(short8*)&Cb[t0 + 1][n0] = *(const short8*)(r0 + XBC);
        *(short8*)&Cb[t0 + 2][n0] = *(const short8*)(r0 + 2 * XBC);
        *(short8*)&Cb[t0 + 3][n0] = *(const short8*)(r0 + 3 * XBC);
      }
    }
    __syncthreads();   // bar1
    if (w == 3) wt[lane] = __expf(la[63] - la[lane]) * dtc[lane];
    short8 afC0 = *(const short8*)&Cb[w * 16 + lr][lj * 8];
    short8 afC1 = *(const short8*)&Cb[w * 16 + lr][32 + lj * 8];
    f32x4 acc_s[4] = {};
#pragma unroll
    for (int ni = 0; ni < 4; ++ni) {
      short8 bf0 = *(const short8*)&Bb[ni * 16 + lr][lj * 8];
      short8 bf1 = *(const short8*)&Bb[ni * 16 + lr][32 + lj * 8];
      acc_s[ni] = __builtin_amdgcn_mfma_f32_16x16x32_bf16(afC0, bf0, acc_s[ni], 0, 0, 0);
      acc_s[ni] = __builtin_amdgcn_mfma_f32_16x16x32_bf16(afC1, bf1, acc_s[ni], 0, 0, 0);
    }
    f32x4 acc_y[2] = {};
#pragma unroll
    for (int ni = 0; ni < 2; ++ni) {
      short8 hf0 = *(const short8*)&hbT[ni * 16 + lr][lj * 8];
      short8 hf1 = *(const short8*)&hbT[ni * 16 + lr][32 + lj * 8];
      acc_y[ni] = __builtin_amdgcn_mfma_f32_16x16x32_bf16(afC0, hf0, acc_y[ni], 0, 0, 0);
      acc_y[ni] = __builtin_amdgcn_mfma_f32_16x16x32_bf16(afC1, hf1, acc_y[ni], 0, 0, 0);
    }
#pragma unroll
    for (int j = 0; j < 4; ++j) {
      float at = __expf(la[w * 16 + lj * 4 + j]);
      acc_y[0][j] *= at;
      acc_y[1][j] *= at;
    }
    __syncthreads();   // bar2
#pragma unroll
    for (int ni = 0; ni < 4; ++ni) {
      int s = ni * 16 + lr;
      float las = la[s], dts = dtc[s];
#pragma unroll
      for (int j = 0; j < 4; ++j) {
        int t = w * 16 + lj * 4 + j;
        float pv = 0.f;
        if (s <= t) pv = acc_s[ni][j] * __expf(la[t] - las) * dts;
        Cb[t][s] = (unsigned short)f2bf(pv);
      }
    }
    __syncthreads();   // bar3
    {
      short8 afP0 = *(const short8*)&Cb[w * 16 + lr][lj * 8];
      short8 afP1 = *(const short8*)&Cb[w * 16 + lr][32 + lj * 8];
#pragma unroll
      for (int ni = 0; ni < 2; ++ni) {
        short8 xf0 = *(const short8*)&xT[ni * 16 + lr][lj * 8];
        short8 xf1 = *(const short8*)&xT[ni * 16 + lr][32 + lj * 8];
        acc_y[ni] = __builtin_amdgcn_mfma_f32_16x16x32_bf16(afP0, xf0, acc_y[ni], 0, 0, 0);
        acc_y[ni] = __builtin_amdgcn_mfma_f32_16x16x32_bf16(afP1, xf1, acc_y[ni], 0, 0, 0);
      }
    }
    if (w < 2) {
      float aend = __expf(la[63]);
#pragma unroll
      for (int ni = 0; ni < 4; ++ni)
#pragma unroll
        for (int j = 0; j < 4; ++j) acc_h[ni][j] *= aend;
#pragma unroll
      for (int kk = 0; kk < 2; ++kk) {
        short8 xv = *(const short8*)&xT[w * 16 + lr][kk * 32 + lj * 8];
        short8 axf;
#pragma unroll
        for (int j = 0; j < 8; ++j)
          axf[j] = f2bf(bf2f((unsigned short)xv[j]) * wt[kk * 32 + lj * 8 + j]);
#pragma unroll
        for (int ni = 0; ni < 4; ++ni) {
          short8 bw = *(const short8*)&BbT[ni * 16 + lr][kk * 32 + lj * 8];
          acc_h[ni] = __builtin_amdgcn_mfma_f32_16x16x32_bf16(axf, bw, acc_h[ni], 0, 0, 0);
        }
      }
    }
#pragma unroll
    for (int ni = 0; ni < 2; ++ni) {
#pragma unroll
      for (int j = 0; j < 4; ++j) {
        int t = w * 16 + lj * 4 + j;
        int p = ni * 16 + lr;
        float yv = acc_y[ni][j] + dph * bf2f(xT[p][t]);
        ysc[(size_t)(tok0 + t) * DI + h * 32 + p] = (unsigned short)f2bf(yv);
      }
    }
    if (w < 2) {
#pragma unroll
      for (int ni = 0; ni < 4; ++ni)
#pragma unroll
        for (int j = 0; j < 4; ++j)
          hbT[w * 16 + lj * 4 + j][ni * 16 + lr] = (unsigned short)f2bf(acc_h[ni][j]);
    }
    __syncthreads();   // bar4
  }
}

// ---------------- y = rmsnorm(y * silu(z)) * nw -> bf16 (y bf16 in) ----------------
__global__ __launch_bounds__(256) void gate_rms_kernel(
    const unsigned short* __restrict__ ysc, const unsigned short* __restrict__ zx,
    const float* __restrict__ nw, unsigned short* __restrict__ yout) {
  int wid = threadIdx.x >> 6, lane = threadIdx.x & 63;
  size_t token = (size_t)blockIdx.x * 4 + wid;
  ushort4 yu = *(const ushort4*)(ysc + token * DI + lane * 4);
  ushort4 zu = *(const ushort4*)(zx + token * DIN + lane * 4);
  float y0 = bf2f(yu.x), y1 = bf2f(yu.y), y2 = bf2f(yu.z), y3 = bf2f(yu.w);
  float z0 = bf2f(zu.x), z1 = bf2f(zu.y), z2 = bf2f(zu.z), z3 = bf2f(zu.w);
  float g0 = y0 * (z0 / (1.f + expf(-z0)));
  float g1 = y1 * (z1 / (1.f + expf(-z1)));
  float g2 = y2 * (z2 / (1.f + expf(-z2)));
  float g3 = y3 * (z3 / (1.f + expf(-z3)));
  float ss = g0 * g0 + g1 * g1 + g2 * g2 + g3 * g3;
#pragma unroll
  for (int off = 1; off < 64; off <<= 1) ss += __shfl_xor(ss, off);
  float r = rsqrtf(ss * (1.f / 256.f) + EPSF);
  unsigned w0 = (unsigned short)f2bf(g0 * r * nw[lane * 4 + 0]);
  unsigned w1 = (unsigned short)f2bf(g1 * r * nw[lane * 4 + 1]);
  unsigned w2 = (unsigned short)f2bf(g2 * r * nw[lane * 4 + 2]);
  unsigned w3 = (unsigned short)f2bf(g3 * r * nw[lane * 4 + 3]);
  uint2 packed = make_uint2(w0 | (w1 << 16), w2 | (w3 << 16));
  *(uint2*)(yout + token * DI + lane * 4) = packed;
}

// ---------------- head: column mean + matmul + L2 normalize (fused) ----------------
__global__ __launch_bounds__(128) void head_kernel(
    const unsigned short* __restrict__ tn, const float* __restrict__ hw,
    const float* __restrict__ hb, float* __restrict__ out) {
  __shared__ float tm[128];
  __shared__ float red[2];
  int b = blockIdx.x, o = threadIdx.x;
  // column mean over L
  {
    const unsigned short* p = tn + (size_t)b * 256 * 128 + o;
    float acc = 0.f;
    for (int l = 0; l < 256; ++l) acc += bf2f(p[l * 128]);
    tm[o] = acc * (1.f / 256.f);
  }
  __syncthreads();
  float acc = hb[o];
  for (int e = 0; e < 128; ++e) acc += tm[e] * hw[o * 128 + e];
  float ss = acc * acc;
#pragma unroll
  for (int off = 1; off < 64; off <<= 1) ss += __shfl_xor(ss, off);
  if ((o & 63) == 0) red[o >> 6] = ss;
  __syncthreads();
  float nrm = fmaxf(sqrtf(red[0] + red[1]), 1e-12f);
  out[b * 128 + o] = acc / nrm;
}

extern "C" void kernel_launch(void* const* d_in, const int* in_sizes, int n_in,
                              void* d_out, int out_size, void* d_ws, size_t ws_size,
                              hipStream_t stream) {
  const float* x      = (const float*)d_in[0];
  const float* conv_w = (const float*)d_in[1];
  const float* conv_b = (const float*)d_in[2];
  const float* pe_w   = (const float*)d_in[3];
  const float* pe_b   = (const float*)d_in[4];
  const float* ln_w   = (const float*)d_in[5];
  const float* ln_b   = (const float*)d_in[6];
  const float* in_w   = (const float*)d_in[7];
  const float* c1w    = (const float*)d_in[8];
  const float* c1b    = (const float*)d_in[9];
  const float* dtb    = (const float*)d_in[10];
  const float* A_log  = (const float*)d_in[11];
  const float* Dp     = (const float*)d_in[12];
  const float* nw     = (const float*)d_in[13];
  const float* ow     = (const float*)d_in[14];
  const float* fn_w   = (const float*)d_in[15];
  const float* fn_b   = (const float*)d_in[16];
  const float* hw     = (const float*)d_in[17];
  const float* hb     = (const float*)d_in[18];
  float* out = (float*)d_out;

  const size_t T = TTOK;
  char* w8 = (char*)d_ws;
  float*          t_buf = (float*)w8;            w8 += T * 128 * 4;   // residual fp32
  unsigned*       tnb   = (unsigned*)w8;         w8 += T * 128 * 2;   // ln out bf16
  unsigned short* zx    = (unsigned short*)w8;   w8 += T * (size_t)DIN * 2; // in-proj bf16
  unsigned short* xbc   = (unsigned short*)w8;   w8 += T * (size_t)XBC * 2; // conv out bf16
  float*          dtraw = (float*)w8;            w8 += T * 8 * 4;
  float*          dtv   = (float*)w8;            w8 += T * 8 * 4;
  float*          ldAv  = (float*)w8;            w8 += T * 8 * 4;
  unsigned short* ysc   = (unsigned short*)w8;   w8 += T * (size_t)DI * 2;  // scan out bf16
  unsigned short* ybb   = (unsigned short*)w8;   w8 += T * (size_t)DI * 2;  // gated bf16
  unsigned short* in_wb = (unsigned short*)w8;   w8 += (size_t)NL * DIN * EE * 2;
  unsigned short* owb   = (unsigned short*)w8;   w8 += (size_t)NL * EE * DI * 2;
  if ((size_t)(w8 - (char*)d_ws) > ws_size) return;  // workspace too small

  // one-shot weight conversion (NL*DIN*EE = 331776 = 1296*256)
  cvt_w_kernel<<<1296, 256, 0, stream>>>(in_w, ow, in_wb, owb);

  // patch embed + bias, then fused pe-LN (fp32) + block-0 LN (bf16)
  gemm_bf16_patch<<<dim3(512, 1), 256, 0, stream>>>(x, conv_w, conv_b, t_buf);
  ln_pe0_kernel<<<16384, 256, 0, stream>>>(t_buf, tnb, pe_w, pe_b, ln_w, ln_b);

  for (int i = 0; i < NL; ++i) {
    gemm_in_proj<<<dim3(6, 512), 256, 0, stream>>>(
        (const unsigned short*)tnb, in_wb + (size_t)i * DIN * EE, zx, dtraw, TTOK, DIN, EE);
    conv_dt_kernel<<<26624, 256, 0, stream>>>(
        zx, c1w + (size_t)i * XBC * DC, c1b + (size_t)i * XBC, xbc,
        dtraw, dtb + i * HH, A_log + i * HH, dtv, ldAv);
    scan_chunk_kernel<<<2048, 256, 0, stream>>>(xbc, dtv, ldAv, Dp + i * HH, ysc);
    gate_rms_kernel<<<16384, 256, 0, stream>>>(ysc, zx, nw + i * DI, ybb);
    const float* nlw = (i < NL - 1) ? (ln_w + (i + 1) * 128) : fn_w;
    const float* nlb = (i < NL - 1) ? (ln_b + (i + 1) * 128) : fn_b;
    gemm_out_ln<<<512, 256, 0, stream>>>(
        ybb, owb + (size_t)i * EE * DI, t_buf, nlw, nlb, tnb);
  }

  // tnb holds final-LN output (fused in last gemm_out_ln)
  head_kernel<<<256, 128, 0, stream>>>((const unsigned short*)tnb, hw, hb, out);
}

// Round 16
// 835.000 us; speedup vs baseline: 1.1533x; 1.0697x over previous
//
#include <hip/hip_runtime.h>
#include <math.h>

// ---------------- constants ----------------
#define EE 128
#define DI 256
#define HH 8
#define PP 32
#define NN 64
#define DC 4
#define XBC 384
#define DIN 648
#define NL 4
#define LSEQ 256
#define BB 256
#define TTOK (BB * LSEQ)   // 65536 tokens
#define EPSF 1e-5f

typedef __attribute__((ext_vector_type(8))) short short8;
typedef __attribute__((ext_vector_type(4))) float f32x4;

__device__ inline short f2bf(float f) {
  unsigned u = __builtin_bit_cast(unsigned, f);
  u += 0x7fff + ((u >> 16) & 1);   // RNE
  return (short)(u >> 16);
}
__device__ inline float bf2f(unsigned short u) {
  unsigned x = ((unsigned)u) << 16;
  return __builtin_bit_cast(float, x);
}

// ---------------- one-shot weight conversion fp32 -> bf16 ----------------
__global__ __launch_bounds__(256) void cvt_w_kernel(
    const float* __restrict__ in_w, const float* __restrict__ ow,
    unsigned short* __restrict__ in_wb, unsigned short* __restrict__ owb) {
  int i = blockIdx.x * 256 + threadIdx.x;   // grid covers NL*DIN*EE = 331776
  in_wb[i] = (unsigned short)f2bf(in_w[i]);
  if (i < NL * EE * DI) owb[i] = (unsigned short)f2bf(ow[i]);
}

// ---------------- in-proj GEMM: bf16 A,B; bf16 out (LDS-coalesced) + fp32 dt side-channel ----------------
// grid = dim3(6, 512): n-tile fastest so the 6 blocks sharing one A-panel are
// dispatch-adjacent (A-panel stays L2-warm).
__global__ __launch_bounds__(256) void gemm_in_proj(
    const unsigned short* __restrict__ A, const unsigned short* __restrict__ B,
    unsigned short* __restrict__ Czx, float* __restrict__ dtraw,
    int M, int N, int K) {
  __shared__ __align__(16) unsigned short smem[128 * 136];
  short (*As)[40] = (short(*)[40])smem;
  short (*Bs)[40] = (short(*)[40])(smem + 128 * 40);
  const int tid = threadIdx.x;
  const int lane = tid & 63, wid = tid >> 6;
  const int wm = wid >> 1, wn = wid & 1;
  const int m0 = blockIdx.y * 128, n0 = blockIdx.x * 128;
  const int r = tid >> 1, hf = tid & 1;
  const int lr = lane & 15, lk = (lane >> 4) * 8;
  f32x4 acc[4][4] = {};
  for (int k0 = 0; k0 < K; k0 += 32) {
    {
      const unsigned short* ap = A + (size_t)(m0 + r) * K + k0 + hf * 16;
      *(short8*)&As[r][hf * 16] = *(const short8*)(ap);
      *(short8*)&As[r][hf * 16 + 8] = *(const short8*)(ap + 8);
    }
    {
      short8 s0 = {}, s1 = {};
      if (n0 + r < N) {
        const unsigned short* bp = B + (size_t)(n0 + r) * K + k0 + hf * 16;
        s0 = *(const short8*)(bp);
        s1 = *(const short8*)(bp + 8);
      }
      *(short8*)&Bs[r][hf * 16] = s0;
      *(short8*)&Bs[r][hf * 16 + 8] = s1;
    }
    __syncthreads();
    short8 af[4], bfr[4];
#pragma unroll
    for (int mi = 0; mi < 4; ++mi) af[mi] = *(const short8*)&As[wm * 64 + mi * 16 + lr][lk];
#pragma unroll
    for (int ni = 0; ni < 4; ++ni) bfr[ni] = *(const short8*)&Bs[wn * 64 + ni * 16 + lr][lk];
#pragma unroll
    for (int mi = 0; mi < 4; ++mi)
#pragma unroll
      for (int ni = 0; ni < 4; ++ni)
        acc[mi][ni] = __builtin_amdgcn_mfma_f32_16x16x32_bf16(af[mi], bfr[ni], acc[mi][ni], 0, 0, 0);
    __syncthreads();
  }
  // epilogue: bf16 tile -> LDS, then coalesced 16B stores
  {
    unsigned short (*Vt)[136] = (unsigned short(*)[136])smem;
#pragma unroll
    for (int mi = 0; mi < 4; ++mi) {
#pragma unroll
      for (int ni = 0; ni < 4; ++ni) {
        int row0 = wm * 64 + mi * 16 + (lane >> 4) * 4;
        int col = wn * 64 + ni * 16 + lr;
#pragma unroll
        for (int j = 0; j < 4; ++j)
          Vt[row0 + j][col] = (unsigned short)f2bf(acc[mi][ni][j]);
      }
    }
    // dt raw side-channel: only tile n0==640, cols 640..647 (wn==0, ni==0, lr<8)
    if (n0 == 640 && wn == 0 && lr < 8) {
#pragma unroll
      for (int mi = 0; mi < 4; ++mi) {
        int row0 = m0 + wm * 64 + mi * 16 + (lane >> 4) * 4;
#pragma unroll
        for (int j = 0; j < 4; ++j)
          dtraw[(size_t)(row0 + j) * 8 + lr] = acc[mi][0][j];
      }
    }
    __syncthreads();
    const int row = tid >> 4, cs = (tid & 15) * 8;
#pragma unroll
    for (int it = 0; it < 8; ++it) {
      int rr2 = it * 16 + row;
      if (n0 + cs < N)
        *(uint4*)(Czx + (size_t)(m0 + rr2) * DIN + n0 + cs) = *(const uint4*)&Vt[rr2][cs];
    }
  }
}

// ---------------- out-proj + residual + fused next-LayerNorm (128-token tile) ----------------
__global__ __launch_bounds__(256) void gemm_out_ln(
    const unsigned short* __restrict__ A, const unsigned short* __restrict__ B,
    float* __restrict__ tres, const float* __restrict__ lnw,
    const float* __restrict__ lnb, unsigned* __restrict__ tnb) {
  __shared__ short As[128][40];
  __shared__ short Bs[128][40];
  __shared__ unsigned short Vt[128][136];
  __shared__ float mu_s[128], rs_s[128];
  const int tid = threadIdx.x;
  const int lane = tid & 63, wid = tid >> 6;
  const int wm = wid >> 1, wn = wid & 1;
  const int m0 = blockIdx.x * 128;
  const int r = tid >> 1, hf = tid & 1;
  const int lr = lane & 15, lk = (lane >> 4) * 8;
  f32x4 acc[4][4] = {};
  for (int k0 = 0; k0 < 256; k0 += 32) {
    {
      const unsigned short* ap = A + (size_t)(m0 + r) * 256 + k0 + hf * 16;
      *(short8*)&As[r][hf * 16] = *(const short8*)(ap);
      *(short8*)&As[r][hf * 16 + 8] = *(const short8*)(ap + 8);
    }
    {
      const unsigned short* bp = B + (size_t)r * 256 + k0 + hf * 16;
      *(short8*)&Bs[r][hf * 16] = *(const short8*)(bp);
      *(short8*)&Bs[r][hf * 16 + 8] = *(const short8*)(bp + 8);
    }
    __syncthreads();
    short8 af[4], bfr[4];
#pragma unroll
    for (int mi = 0; mi < 4; ++mi) af[mi] = *(const short8*)&As[wm * 64 + mi * 16 + lr][lk];
#pragma unroll
    for (int ni = 0; ni < 4; ++ni) bfr[ni] = *(const short8*)&Bs[wn * 64 + ni * 16 + lr][lk];
#pragma unroll
    for (int mi = 0; mi < 4; ++mi)
#pragma unroll
      for (int ni = 0; ni < 4; ++ni)
        acc[mi][ni] = __builtin_amdgcn_mfma_f32_16x16x32_bf16(af[mi], bfr[ni], acc[mi][ni], 0, 0, 0);
    __syncthreads();
  }
  // epilogue: residual add, fp32 store, bf16 LDS tile
#pragma unroll
  for (int mi = 0; mi < 4; ++mi) {
#pragma unroll
    for (int ni = 0; ni < 4; ++ni) {
      int row0 = wm * 64 + mi * 16 + (lane >> 4) * 4;
      int col = wn * 64 + ni * 16 + lr;
#pragma unroll
      for (int j = 0; j < 4; ++j) {
        int row = row0 + j;
        size_t idx = (size_t)(m0 + row) * 128 + col;
        float v = acc[mi][ni][j] + tres[idx];
        tres[idx] = v;
        Vt[row][col] = (unsigned short)f2bf(v);
      }
    }
  }
  __syncthreads();
  // per-row stats (2 threads per row)
  {
    int row = tid >> 1;
    float s = 0.f, ss = 0.f;
#pragma unroll
    for (int kk = 0; kk < 8; ++kk) {
      short8 vv = *(const short8*)&Vt[row][hf * 64 + kk * 8];
#pragma unroll
      for (int j = 0; j < 8; ++j) {
        float f = bf2f((unsigned short)vv[j]);
        s += f; ss += f * f;
      }
    }
    s += __shfl_xor(s, 1);
    ss += __shfl_xor(ss, 1);
    if (hf == 0) {
      float mu = s * (1.f / 128.f);
      mu_s[row] = mu;
      rs_s[row] = rsqrtf(ss * (1.f / 128.f) - mu * mu + EPSF);
    }
  }
  __syncthreads();
  // LN write: packed bf16, coalesced
  float w0 = lnw[lane * 2], w1 = lnw[lane * 2 + 1];
  float b0 = lnb[lane * 2], b1 = lnb[lane * 2 + 1];
  for (int it = 0; it < 32; ++it) {
    int row = it * 4 + wid;
    float mu = mu_s[row], rr = rs_s[row];
    float v0 = bf2f(Vt[row][lane * 2]);
    float v1 = bf2f(Vt[row][lane * 2 + 1]);
    unsigned lo = (unsigned short)f2bf((v0 - mu) * rr * w0 + b0);
    unsigned hi = (unsigned short)f2bf((v1 - mu) * rr * w1 + b1);
    tnb[(size_t)(m0 + row) * 64 + lane] = lo | (hi << 16);
  }
}

// ---------------- patch-embed bf16 MFMA GEMM ----------------
__global__ __launch_bounds__(256) void gemm_bf16_patch(
    const float* __restrict__ X, const float* __restrict__ B,
    const float* __restrict__ bias, float* __restrict__ C) {
  __shared__ short As[128][40];
  __shared__ short Bs[128][40];
  const int tid = threadIdx.x;
  const int lane = tid & 63, wid = tid >> 6;
  const int wm = wid >> 1, wn = wid & 1;
  const int m0 = blockIdx.x * 128;
  const int r = tid >> 1, hf = tid & 1;
  const int lr = lane & 15, lk = (lane >> 4) * 8;
  const int m = m0 + r;
  const int bb = m >> 8, px = (m >> 4) & 15, py = m & 15;
  f32x4 acc[4][4] = {};
  for (int k0 = 0; k0 < 768; k0 += 32) {
    int k = k0 + hf * 16;
    int c = k >> 8, dx = (k >> 4) & 15;
    {
      const float* ap = X + (((size_t)(bb * 3 + c) * 256 + px * 16 + dx) * 256 + py * 16);
      float4 v0 = *(const float4*)(ap + 0);
      float4 v1 = *(const float4*)(ap + 4);
      float4 v2 = *(const float4*)(ap + 8);
      float4 v3 = *(const float4*)(ap + 12);
      short8 s0, s1;
      s0[0] = f2bf(v0.x); s0[1] = f2bf(v0.y); s0[2] = f2bf(v0.z); s0[3] = f2bf(v0.w);
      s0[4] = f2bf(v1.x); s0[5] = f2bf(v1.y); s0[6] = f2bf(v1.z); s0[7] = f2bf(v1.w);
      s1[0] = f2bf(v2.x); s1[1] = f2bf(v2.y); s1[2] = f2bf(v2.z); s1[3] = f2bf(v2.w);
      s1[4] = f2bf(v3.x); s1[5] = f2bf(v3.y); s1[6] = f2bf(v3.z); s1[7] = f2bf(v3.w);
      *(short8*)&As[r][hf * 16] = s0;
      *(short8*)&As[r][hf * 16 + 8] = s1;
    }
    {
      const float* bp = B + (size_t)r * 768 + k;
      float4 v0 = *(const float4*)(bp + 0);
      float4 v1 = *(const float4*)(bp + 4);
      float4 v2 = *(const float4*)(bp + 8);
      float4 v3 = *(const float4*)(bp + 12);
      short8 s0, s1;
      s0[0] = f2bf(v0.x); s0[1] = f2bf(v0.y); s0[2] = f2bf(v0.z); s0[3] = f2bf(v0.w);
      s0[4] = f2bf(v1.x); s0[5] = f2bf(v1.y); s0[6] = f2bf(v1.z); s0[7] = f2bf(v1.w);
      s1[0] = f2bf(v2.x); s1[1] = f2bf(v2.y); s1[2] = f2bf(v2.z); s1[3] = f2bf(v2.w);
      s1[4] = f2bf(v3.x); s1[5] = f2bf(v3.y); s1[6] = f2bf(v3.z); s1[7] = f2bf(v3.w);
      *(short8*)&Bs[r][hf * 16] = s0;
      *(short8*)&Bs[r][hf * 16 + 8] = s1;
    }
    __syncthreads();
    short8 af[4], bfr[4];
#pragma unroll
    for (int mi = 0; mi < 4; ++mi) af[mi] = *(const short8*)&As[wm * 64 + mi * 16 + lr][lk];
#pragma unroll
    for (int ni = 0; ni < 4; ++ni) bfr[ni] = *(const short8*)&Bs[wn * 64 + ni * 16 + lr][lk];
#pragma unroll
    for (int mi = 0; mi < 4; ++mi)
#pragma unroll
      for (int ni = 0; ni < 4; ++ni)
        acc[mi][ni] = __builtin_amdgcn_mfma_f32_16x16x32_bf16(af[mi], bfr[ni], acc[mi][ni], 0, 0, 0);
    __syncthreads();
  }
#pragma unroll
  for (int mi = 0; mi < 4; ++mi) {
#pragma unroll
    for (int ni = 0; ni < 4; ++ni) {
      int row0 = m0 + wm * 64 + mi * 16 + (lane >> 4) * 4;
      int col = wn * 64 + ni * 16 + (lane & 15);
#pragma unroll
      for (int j = 0; j < 4; ++j)
        C[(size_t)(row0 + j) * 128 + col] = acc[mi][ni][j] + bias[col];
    }
  }
}

// ---------------- fused pe-LN (fp32, in place) + block-0 LN (bf16 out) ----------------
__global__ __launch_bounds__(256) void ln_pe0_kernel(
    float* t, unsigned* out,
    const float* __restrict__ pe_w, const float* __restrict__ pe_b,
    const float* __restrict__ l0w, const float* __restrict__ l0b) {
  int wid = threadIdx.x >> 6, lane = threadIdx.x & 63;
  size_t token = (size_t)blockIdx.x * 4 + wid;
  float* p = t + token * 128;
  float2 v = *(const float2*)(p + lane * 2);
  // pe-LN
  float s = v.x + v.y;
#pragma unroll
  for (int off = 1; off < 64; off <<= 1) s += __shfl_xor(s, off);
  float mu = s * (1.f / 128.f);
  float dx = v.x - mu, dy = v.y - mu;
  float vs = dx * dx + dy * dy;
#pragma unroll
  for (int off = 1; off < 64; off <<= 1) vs += __shfl_xor(vs, off);
  float r = rsqrtf(vs * (1.f / 128.f) + EPSF);
  float t0 = dx * r * pe_w[lane * 2 + 0] + pe_b[lane * 2 + 0];
  float t1 = dy * r * pe_w[lane * 2 + 1] + pe_b[lane * 2 + 1];
  *(float2*)(p + lane * 2) = make_float2(t0, t1);
  // block-0 LN on (t0, t1)
  float s2 = t0 + t1;
#pragma unroll
  for (int off = 1; off < 64; off <<= 1) s2 += __shfl_xor(s2, off);
  float mu2 = s2 * (1.f / 128.f);
  float d0 = t0 - mu2, d1 = t1 - mu2;
  float vs2 = d0 * d0 + d1 * d1;
#pragma unroll
  for (int off = 1; off < 64; off <<= 1) vs2 += __shfl_xor(vs2, off);
  float r2 = rsqrtf(vs2 * (1.f / 128.f) + EPSF);
  unsigned lo = (unsigned short)f2bf(d0 * r2 * l0w[lane * 2 + 0] + l0b[lane * 2 + 0]);
  unsigned hi = (unsigned short)f2bf(d1 * r2 * l0w[lane * 2 + 1] + l0b[lane * 2 + 1]);
  out[token * 64 + lane] = lo | (hi << 16);
}

// ---------------- chunked SSM scan via MFMA; conv1d+SiLU and dt fused into staging ----------------
// grid = 2048; b = bid&255, h = bid>>8. Stages read zx (in-proj output) directly:
// each 4-token x 8-channel quad loads 7 tap-rows and computes conv+SiLU in regs.
// dt/ldA computed in wave-0 prefix pass from dtraw. xbc buffer + conv kernel deleted.
__global__ __launch_bounds__(256, 4) void scan_chunk_kernel(
    const unsigned short* __restrict__ zx,   // [T][648] bf16 (cols 256.. = pre-conv xbc)
    const float* __restrict__ dtraw,         // [T][8] fp32
    const float* __restrict__ dtb,           // [8]
    const float* __restrict__ A_log,         // [8]
    const float* __restrict__ cw,            // [384][4] conv weights
    const float* __restrict__ cbv_g,         // [384] conv bias
    const float* __restrict__ Dp,            // [8]
    unsigned short* __restrict__ ysc) {      // [T][256] bf16
  const int b = blockIdx.x & 255, h = blockIdx.x >> 8;
  const int tid = threadIdx.x;
  const int w = tid >> 6, lane = tid & 63;
  const int lr = lane & 15, lj = lane >> 4;
  __shared__ __align__(16) unsigned short Cb[64][72];   // C rows [t][n]; P after phase1
  __shared__ __align__(16) unsigned short Bb[64][72];   // B rows [s][n]
  __shared__ __align__(16) unsigned short BbT[64][72];  // [n][s]
  __shared__ __align__(16) unsigned short xT[32][72];   // [p][t]
  __shared__ __align__(16) unsigned short hbT[32][72];  // h [p][n]
  __shared__ float la[64], dtc[64], wt[64];
  for (int i = tid; i < 32 * 72 / 2; i += 256) ((unsigned*)hbT)[i] = 0;
  f32x4 acc_h[4] = {};   // waves 0,1 own h rows p = w*16 .. w*16+15
  const float dph = Dp[h];
  const float dtb_h = dtb[h];
  const float expA_h = expf(A_log[h]);
  __syncthreads();

  for (int c = 0; c < 4; ++c) {
    const int tok0 = b * 256 + c * 64;
    // ---- dt + prefix-scan (wave 0) ----
    if (w == 0) {
      float raw = dtraw[(size_t)(tok0 + lane) * 8 + h] + dtb_h;
      float dt = raw > 20.f ? raw : log1pf(expf(raw));
      float v = -expA_h * dt;
#pragma unroll
      for (int off = 1; off < 64; off <<= 1) {
        float u = __shfl_up(v, off);
        if (lane >= off) v += u;
      }
      la[lane] = v;
      dtc[lane] = dt;
    }
    // ---- staging with fused conv1d + SiLU ----
    for (int it = tid; it < 320; it += 256) {
      int t0, ch;   // ch = xbc-channel base (0..376)
      if (it < 64) {
        int pq = it & 3, tq = it >> 2;
        t0 = tq * 4; ch = h * 32 + pq * 8;
      } else if (it < 192) {
        int id = it - 64;
        t0 = (id >> 3) * 4; ch = 256 + (id & 7) * 8;
      } else {
        int id = it - 192;
        t0 = (id >> 3) * 4; ch = 320 + (id & 7) * 8;
      }
      const unsigned short* zp = zx + (size_t)(tok0 + t0) * DIN + 256 + ch;
      const int t0loc = c * 64 + t0;
      short8 rr[7];
#pragma unroll
      for (int d = 0; d < 7; ++d) {
        short8 z8 = {};
        if (t0loc + d - 3 >= 0) z8 = *(const short8*)(zp + (ptrdiff_t)(d - 3) * DIN);
        rr[d] = z8;
      }
      float4 cwv[8];
      float cbl[8];
#pragma unroll
      for (int j = 0; j < 8; ++j) {
        cwv[j] = *(const float4*)(cw + (ch + j) * 4);
        cbl[j] = cbv_g[ch + j];
      }
      short8 o[4];
#pragma unroll
      for (int tt = 0; tt < 4; ++tt) {
#pragma unroll
        for (int j = 0; j < 8; ++j) {
          float a = cbl[j]
                  + cwv[j].x * bf2f((unsigned short)rr[tt + 0][j])
                  + cwv[j].y * bf2f((unsigned short)rr[tt + 1][j])
                  + cwv[j].z * bf2f((unsigned short)rr[tt + 2][j])
                  + cwv[j].w * bf2f((unsigned short)rr[tt + 3][j]);
          a = a / (1.f + __expf(-a));
          o[tt][j] = f2bf(a);
        }
      }
      if (it < 64) {
        int p0 = ch - h * 32;
#pragma unroll
        for (int j = 0; j < 8; ++j) {
          ushort4 v;
          v.x = (unsigned short)o[0][j]; v.y = (unsigned short)o[1][j];
          v.z = (unsigned short)o[2][j]; v.w = (unsigned short)o[3][j];
          *(ushort4*)&xT[p0 + j][t0] = v;
        }
      } else if (it < 192) {
        int n0 = ch - 256;
        *(short8*)&Bb[t0 + 0][n0] = o[0];
        *(short8*)&Bb[t0 + 1][n0] = o[1];
        *(short8*)&Bb[t0 + 2][n0] = o[2];
        *(short8*)&Bb[t0 + 3][n0] = o[3];
#pragma unroll
        for (int j = 0; j < 8; ++j) {
          ushort4 v;
          v.x = (unsigned short)o[0][j]; v.y = (unsigned short)o[1][j];
          v.z = (unsigned short)o[2][j]; v.w = (unsigned short)o[3][j];
          *(ushort4*)&BbT[n0 + j][t0] = v;
        }
      } else {
        int n0 = ch - 320;
        *(short8*)&Cb[t0 + 0][n0] = o[0];
        *(short8*)&Cb[t0 + 1][n0] = o[1];
        *(short8*)&Cb[t0 + 2][n0] = o[2];
        *(short8*)&Cb[t0 + 3][n0] = o[3];
      }
    }
    __syncthreads();   // bar1
    if (w == 3) wt[lane] = __expf(la[63] - la[lane]) * dtc[lane];
    short8 afC0 = *(const short8*)&Cb[w * 16 + lr][lj * 8];
    short8 afC1 = *(const short8*)&Cb[w * 16 + lr][32 + lj * 8];
    f32x4 acc_s[4] = {};
#pragma unroll
    for (int ni = 0; ni < 4; ++ni) {
      short8 bf0 = *(const short8*)&Bb[ni * 16 + lr][lj * 8];
      short8 bf1 = *(const short8*)&Bb[ni * 16 + lr][32 + lj * 8];
      acc_s[ni] = __builtin_amdgcn_mfma_f32_16x16x32_bf16(afC0, bf0, acc_s[ni], 0, 0, 0);
      acc_s[ni] = __builtin_amdgcn_mfma_f32_16x16x32_bf16(afC1, bf1, acc_s[ni], 0, 0, 0);
    }
    f32x4 acc_y[2] = {};
#pragma unroll
    for (int ni = 0; ni < 2; ++ni) {
      short8 hf0 = *(const short8*)&hbT[ni * 16 + lr][lj * 8];
      short8 hf1 = *(const short8*)&hbT[ni * 16 + lr][32 + lj * 8];
      acc_y[ni] = __builtin_amdgcn_mfma_f32_16x16x32_bf16(afC0, hf0, acc_y[ni], 0, 0, 0);
      acc_y[ni] = __builtin_amdgcn_mfma_f32_16x16x32_bf16(afC1, hf1, acc_y[ni], 0, 0, 0);
    }
#pragma unroll
    for (int j = 0; j < 4; ++j) {
      float at = __expf(la[w * 16 + lj * 4 + j]);
      acc_y[0][j] *= at;
      acc_y[1][j] *= at;
    }
    __syncthreads();   // bar2
#pragma unroll
    for (int ni = 0; ni < 4; ++ni) {
      int s = ni * 16 + lr;
      float las = la[s], dts = dtc[s];
#pragma unroll
      for (int j = 0; j < 4; ++j) {
        int t = w * 16 + lj * 4 + j;
        float pv = 0.f;
        if (s <= t) pv = acc_s[ni][j] * __expf(la[t] - las) * dts;
        Cb[t][s] = (unsigned short)f2bf(pv);
      }
    }
    __syncthreads();   // bar3
    {
      short8 afP0 = *(const short8*)&Cb[w * 16 + lr][lj * 8];
      short8 afP1 = *(const short8*)&Cb[w * 16 + lr][32 + lj * 8];
#pragma unroll
      for (int ni = 0; ni < 2; ++ni) {
        short8 xf0 = *(const short8*)&xT[ni * 16 + lr][lj * 8];
        short8 xf1 = *(const short8*)&xT[ni * 16 + lr][32 + lj * 8];
        acc_y[ni] = __builtin_amdgcn_mfma_f32_16x16x32_bf16(afP0, xf0, acc_y[ni], 0, 0, 0);
        acc_y[ni] = __builtin_amdgcn_mfma_f32_16x16x32_bf16(afP1, xf1, acc_y[ni], 0, 0, 0);
      }
    }
    if (w < 2) {
      float aend = __expf(la[63]);
#pragma unroll
      for (int ni = 0; ni < 4; ++ni)
#pragma unroll
        for (int j = 0; j < 4; ++j) acc_h[ni][j] *= aend;
#pragma unroll
      for (int kk = 0; kk < 2; ++kk) {
        short8 xv = *(const short8*)&xT[w * 16 + lr][kk * 32 + lj * 8];
        short8 axf;
#pragma unroll
        for (int j = 0; j < 8; ++j)
          axf[j] = f2bf(bf2f((unsigned short)xv[j]) * wt[kk * 32 + lj * 8 + j]);
#pragma unroll
        for (int ni = 0; ni < 4; ++ni) {
          short8 bw = *(const short8*)&BbT[ni * 16 + lr][kk * 32 + lj * 8];
          acc_h[ni] = __builtin_amdgcn_mfma_f32_16x16x32_bf16(axf, bw, acc_h[ni], 0, 0, 0);
        }
      }
    }
#pragma unroll
    for (int ni = 0; ni < 2; ++ni) {
#pragma unroll
      for (int j = 0; j < 4; ++j) {
        int t = w * 16 + lj * 4 + j;
        int p = ni * 16 + lr;
        float yv = acc_y[ni][j] + dph * bf2f(xT[p][t]);
        ysc[(size_t)(tok0 + t) * DI + h * 32 + p] = (unsigned short)f2bf(yv);
      }
    }
    if (w < 2) {
#pragma unroll
      for (int ni = 0; ni < 4; ++ni)
#pragma unroll
        for (int j = 0; j < 4; ++j)
          hbT[w * 16 + lj * 4 + j][ni * 16 + lr] = (unsigned short)f2bf(acc_h[ni][j]);
    }
    __syncthreads();   // bar4
  }
}

// ---------------- y = rmsnorm(y * silu(z)) * nw -> bf16 (y bf16 in) ----------------
__global__ __launch_bounds__(256) void gate_rms_kernel(
    const unsigned short* __restrict__ ysc, const unsigned short* __restrict__ zx,
    const float* __restrict__ nw, unsigned short* __restrict__ yout) {
  int wid = threadIdx.x >> 6, lane = threadIdx.x & 63;
  size_t token = (size_t)blockIdx.x * 4 + wid;
  ushort4 yu = *(const ushort4*)(ysc + token * DI + lane * 4);
  ushort4 zu = *(const ushort4*)(zx + token * DIN + lane * 4);
  float y0 = bf2f(yu.x), y1 = bf2f(yu.y), y2 = bf2f(yu.z), y3 = bf2f(yu.w);
  float z0 = bf2f(zu.x), z1 = bf2f(zu.y), z2 = bf2f(zu.z), z3 = bf2f(zu.w);
  float g0 = y0 * (z0 / (1.f + expf(-z0)));
  float g1 = y1 * (z1 / (1.f + expf(-z1)));
  float g2 = y2 * (z2 / (1.f + expf(-z2)));
  float g3 = y3 * (z3 / (1.f + expf(-z3)));
  float ss = g0 * g0 + g1 * g1 + g2 * g2 + g3 * g3;
#pragma unroll
  for (int off = 1; off < 64; off <<= 1) ss += __shfl_xor(ss, off);
  float r = rsqrtf(ss * (1.f / 256.f) + EPSF);
  unsigned w0 = (unsigned short)f2bf(g0 * r * nw[lane * 4 + 0]);
  unsigned w1 = (unsigned short)f2bf(g1 * r * nw[lane * 4 + 1]);
  unsigned w2 = (unsigned short)f2bf(g2 * r * nw[lane * 4 + 2]);
  unsigned w3 = (unsigned short)f2bf(g3 * r * nw[lane * 4 + 3]);
  uint2 packed = make_uint2(w0 | (w1 << 16), w2 | (w3 << 16));
  *(uint2*)(yout + token * DI + lane * 4) = packed;
}

// ---------------- head: column mean + matmul + L2 normalize (fused) ----------------
__global__ __launch_bounds__(128) void head_kernel(
    const unsigned short* __restrict__ tn, const float* __restrict__ hw,
    const float* __restrict__ hb, float* __restrict__ out) {
  __shared__ float tm[128];
  __shared__ float red[2];
  int b = blockIdx.x, o = threadIdx.x;
  // column mean over L
  {
    const unsigned short* p = tn + (size_t)b * 256 * 128 + o;
    float acc = 0.f;
    for (int l = 0; l < 256; ++l) acc += bf2f(p[l * 128]);
    tm[o] = acc * (1.f / 256.f);
  }
  __syncthreads();
  float acc = hb[o];
  for (int e = 0; e < 128; ++e) acc += tm[e] * hw[o * 128 + e];
  float ss = acc * acc;
#pragma unroll
  for (int off = 1; off < 64; off <<= 1) ss += __shfl_xor(ss, off);
  if ((o & 63) == 0) red[o >> 6] = ss;
  __syncthreads();
  float nrm = fmaxf(sqrtf(red[0] + red[1]), 1e-12f);
  out[b * 128 + o] = acc / nrm;
}

extern "C" void kernel_launch(void* const* d_in, const int* in_sizes, int n_in,
                              void* d_out, int out_size, void* d_ws, size_t ws_size,
                              hipStream_t stream) {
  const float* x      = (const float*)d_in[0];
  const float* conv_w = (const float*)d_in[1];
  const float* conv_b = (const float*)d_in[2];
  const float* pe_w   = (const float*)d_in[3];
  const float* pe_b   = (const float*)d_in[4];
  const float* ln_w   = (const float*)d_in[5];
  const float* ln_b   = (const float*)d_in[6];
  const float* in_w   = (const float*)d_in[7];
  const float* c1w    = (const float*)d_in[8];
  const float* c1b    = (const float*)d_in[9];
  const float* dtb    = (const float*)d_in[10];
  const float* A_log  = (const float*)d_in[11];
  const float* Dp     = (const float*)d_in[12];
  const float* nw     = (const float*)d_in[13];
  const float* ow     = (const float*)d_in[14];
  const float* fn_w   = (const float*)d_in[15];
  const float* fn_b   = (const float*)d_in[16];
  const float* hw     = (const float*)d_in[17];
  const float* hb     = (const float*)d_in[18];
  float* out = (float*)d_out;

  const size_t T = TTOK;
  char* w8 = (char*)d_ws;
  float*          t_buf = (float*)w8;            w8 += T * 128 * 4;   // residual fp32
  unsigned*       tnb   = (unsigned*)w8;         w8 += T * 128 * 2;   // ln out bf16
  unsigned short* zx    = (unsigned short*)w8;   w8 += T * (size_t)DIN * 2; // in-proj bf16
  float*          dtraw = (float*)w8;            w8 += T * 8 * 4;
  unsigned short* ysc   = (unsigned short*)w8;   w8 += T * (size_t)DI * 2;  // scan out bf16
  unsigned short* ybb   = (unsigned short*)w8;   w8 += T * (size_t)DI * 2;  // gated bf16
  unsigned short* in_wb = (unsigned short*)w8;   w8 += (size_t)NL * DIN * EE * 2;
  unsigned short* owb   = (unsigned short*)w8;   w8 += (size_t)NL * EE * DI * 2;
  if ((size_t)(w8 - (char*)d_ws) > ws_size) return;  // workspace too small

  // one-shot weight conversion (NL*DIN*EE = 331776 = 1296*256)
  cvt_w_kernel<<<1296, 256, 0, stream>>>(in_w, ow, in_wb, owb);

  // patch embed + bias, then fused pe-LN (fp32) + block-0 LN (bf16)
  gemm_bf16_patch<<<dim3(512, 1), 256, 0, stream>>>(x, conv_w, conv_b, t_buf);
  ln_pe0_kernel<<<16384, 256, 0, stream>>>(t_buf, tnb, pe_w, pe_b, ln_w, ln_b);

  for (int i = 0; i < NL; ++i) {
    gemm_in_proj<<<dim3(6, 512), 256, 0, stream>>>(
        (const unsigned short*)tnb, in_wb + (size_t)i * DIN * EE, zx, dtraw, TTOK, DIN, EE);
    scan_chunk_kernel<<<2048, 256, 0, stream>>>(
        zx, dtraw, dtb + i * HH, A_log + i * HH,
        c1w + (size_t)i * XBC * DC, c1b + (size_t)i * XBC, Dp + i * HH, ysc);
    gate_rms_kernel<<<16384, 256, 0, stream>>>(ysc, zx, nw + i * DI, ybb);
    const float* nlw = (i < NL - 1) ? (ln_w + (i + 1) * 128) : fn_w;
    const float* nlb = (i < NL - 1) ? (ln_b + (i + 1) * 128) : fn_b;
    gemm_out_ln<<<512, 256, 0, stream>>>(
        ybb, owb + (size_t)i * EE * DI, t_buf, nlw, nlb, tnb);
  }

  // tnb holds final-LN output (fused in last gemm_out_ln)
  head_kernel<<<256, 128, 0, stream>>>((const unsigned short*)tnb, hw, hb, out);
}